// Round 10
// baseline (331.774 us; speedup 1.0000x reference)
//
#include <hip/hip_runtime.h>
#include <hip/hip_bf16.h>
#include <hip/hip_fp16.h>
#include <math.h>

// SGC: out = log_softmax( S^2 X W^T + b ), S = D^-1/2 (A+I) D^-1/2
// t0 = dis .* (X W^T) in *f16* (pre-scaled 80 B rows).
// Props: src-range pass split (each pass gathers one 4 MB table half ->
// L2-resident) x group-per-node gather (5-lane group per dst, 12 nodes/wave,
// f32 accum, no folds). NEW (round 10): NONTEMPORAL hints on all streaming
// accesses in the prop kernels (srcsB offset loads, partial write/read,
// final stores) so the streams stop evicting the L2-resident table half.
// r4 counters showed 32 MB/pass of table RE-fetch (54 MB FETCH vs ~22
// compulsory) -- the half fits L2 exactly but isn't protected.
// CSR build: round-7 block-local LDS counting sort (P3BLK=6250, measured
// optimum; r8 occupancy probe and r9 atomic-rotation probe were both null,
// so r7's simplest form is restored verbatim).
// p4 reads tmp[b*CAP + i], 512-key (dstLocal*2 + srcHalf) counting sort.

#define N_NODES 100000
#define N_FEAT  128
#define N_CLASS 40

#define RANGE   256           // dsts per fine bucket (pow2: dst>>8)
#define NBALLOC 512
#define NBUSED  391           // ceil(100000/256)
#define CAP     8704          // fine bucket cap (mean 8192 + ~5.7 sigma)
#define P3BLK   6250          // edges per p3a block (grid = ceil(E/P3BLK))
#define HALF_SPLIT 50000      // src-range split point (table half = 4 MB)

typedef __attribute__((ext_vector_type(8))) short short8;   // 8 bf16 (4 VGPRs)
typedef __attribute__((ext_vector_type(4))) float floatx4;  // f32x4 (NT-able)
typedef __attribute__((ext_vector_type(4))) int intx4;      // i32x4 (NT-able)
typedef __attribute__((ext_vector_type(4))) unsigned int uintx4;

// ---------------------------------------------------------------------------
// Detect int32 vs int64 edge_index words; zero bucket counters. 1 block x 512.
__global__ void detect_zero_kernel(const int* __restrict__ ei, int* __restrict__ flag,
                                   int* __restrict__ bucketCount) {
    int t = threadIdx.x;
    if (t < NBALLOC) bucketCount[t] = 0;
    if (t < 64) {
        int nz = (ei[2 * t + 1] != 0) ? 1 : 0;
        unsigned long long b = __ballot(nz);
        if (t == 0) *flag = (b == 0ull) ? 1 : 0;   // 1 => int64 layout
    }
}

__device__ __forceinline__ int edge_word(const int* ei, int elem, int is64) {
    return is64 ? ei[2 * elem] : ei[elem];
}

// P3a: block-local LDS counting sort over 512 fine buckets, then coalesced
// bucket-grouped run writes into fixed-stride regions tmp[f*CAP + p].
// bucketCount accumulates global per-bucket totals (scanned by p2).
__global__ __launch_bounds__(256) void p3a_scatter(
    const int* __restrict__ ei, int E, const int* __restrict__ flag,
    int* __restrict__ bucketCount, unsigned int* __restrict__ tmp)
{
    __shared__ unsigned int srt[P3BLK];     // bucket-grouped records
    __shared__ unsigned short fb[P3BLK];    // bucket id per record
    __shared__ int hist[NBALLOC];
    __shared__ int lbase[NBALLOC];          // block-local exclusive scan
    __shared__ int gbase[NBALLOC];          // global run base per bucket
    __shared__ int cur[NBALLOC];
    __shared__ int sc[256];
    int t = threadIdx.x;
    for (int i = t; i < NBALLOC; i += 256) hist[i] = 0;
    __syncthreads();
    int is64 = *flag;
    int per = (E + gridDim.x - 1) / gridDim.x;
    int e0 = blockIdx.x * per;
    int e1 = min(E, e0 + per);
    int n = e1 - e0;
    for (int e = e0 + t; e < e1; e += 256) {
        int c = edge_word(ei, E + e, is64);
        atomicAdd(&hist[c >> 8], 1);
    }
    __syncthreads();
    int h0 = hist[2 * t], h1 = hist[2 * t + 1];
    sc[t] = h0 + h1;
    __syncthreads();
    for (int o = 1; o < 256; o <<= 1) {
        int y = (t >= o) ? sc[t - o] : 0;
        __syncthreads();
        sc[t] += y;
        __syncthreads();
    }
    int excl = sc[t] - (h0 + h1);
    lbase[2 * t] = excl;
    lbase[2 * t + 1] = excl + h0;
    cur[2 * t] = excl;
    cur[2 * t + 1] = excl + h0;
    gbase[2 * t]     = h0 ? atomicAdd(&bucketCount[2 * t], h0) : 0;
    gbase[2 * t + 1] = h1 ? atomicAdd(&bucketCount[2 * t + 1], h1) : 0;
    __syncthreads();
    for (int e = e0 + t; e < e1; e += 256) {
        int c = edge_word(ei, E + e, is64);
        int r = edge_word(ei, e, is64);
        int f = c >> 8;
        int p = atomicAdd(&cur[f], 1);
        srt[p] = ((unsigned)(c & 255) << 24) | (unsigned)r;
        fb[p] = (unsigned short)f;
    }
    __syncthreads();
    for (int i = t; i < n; i += 256) {
        int f = fb[i];
        int p = gbase[f] + (i - lbase[f]);
        if (p < CAP) tmp[(size_t)f * CAP + p] = srt[i];
    }
}

// P2: scan fine counts -> bucketStart; starts[N]=E.
__global__ __launch_bounds__(NBALLOC) void p2_scan(
    const int* __restrict__ bucketCount, int* __restrict__ bucketStart,
    int* __restrict__ starts, int E)
{
    __shared__ int s[NBALLOC];
    int t = threadIdx.x;
    int v = bucketCount[t];
    s[t] = v;
    __syncthreads();
    for (int o = 1; o < NBALLOC; o <<= 1) {
        int y = (t >= o) ? s[t - o] : 0;
        __syncthreads();
        s[t] += y;
        __syncthreads();
    }
    int incl = s[t], excl = incl - v;
    bucketStart[t] = excl;
    if (t == NBALLOC - 1) { bucketStart[NBALLOC] = incl; starts[N_NODES] = E; }
}

// P4: per-fine-bucket LDS counting sort with 512 keys (dlf*2 + srcHalf) ->
// starts, mid (end of half0 / begin of half1), dis, srcsB (byte offsets,
// src*80, coalesced). Records come from tmp[b*CAP + i] (region-stride).
__global__ __launch_bounds__(256) void p4_sort(
    const unsigned int* __restrict__ tmp, const int* __restrict__ bucketStart,
    int* __restrict__ starts, int* __restrict__ mid, float* __restrict__ dis,
    int* __restrict__ srcsB, int N)
{
    __shared__ int srt[CAP];
    __shared__ int hist[512];
    __shared__ int sc[256];
    __shared__ int cur[512];
    int b = blockIdx.x, t = threadIdx.x;
    int g0 = b * RANGE;
    int gcnt = N - g0;
    if (gcnt > RANGE) gcnt = RANGE;
    int base = bucketStart[b];
    int n = bucketStart[b + 1] - base;
    int nr = min(n, CAP);                       // records actually present
    const unsigned int* rec = tmp + (size_t)b * CAP;
    hist[t] = 0;
    hist[t + 256] = 0;
    __syncthreads();
    for (int i = t; i < nr; i += 256) {
        unsigned v = rec[i];
        int key = (int)((v >> 24) << 1) | (((v & 0xFFFFFFu) >= HALF_SPLIT) ? 1 : 0);
        atomicAdd(&hist[key], 1);
    }
    __syncthreads();
    int c0 = hist[2 * t], c1 = hist[2 * t + 1];
    sc[t] = c0 + c1;
    __syncthreads();
    for (int o = 1; o < 256; o <<= 1) {
        int y = (t >= o) ? sc[t - o] : 0;
        __syncthreads();
        sc[t] += y;
        __syncthreads();
    }
    int excl = sc[t] - (c0 + c1);
    if (t < gcnt) {
        starts[g0 + t] = base + excl;
        mid[g0 + t] = base + excl + c0;
        dis[g0 + t] = rsqrtf((float)(c0 + c1 + 1));   // +1 self-loop
    }
    cur[2 * t] = excl;
    cur[2 * t + 1] = excl + c0;
    __syncthreads();
    for (int i = t; i < nr; i += 256) {
        unsigned v = rec[i];
        int src = (int)(v & 0xFFFFFFu);
        int key = (int)((v >> 24) << 1) | ((src >= HALF_SPLIT) ? 1 : 0);
        int p = atomicAdd(&cur[key], 1);
        srt[p] = src * 80;                       // pre-scaled byte offset
    }
    __syncthreads();
    for (int i = t; i < nr; i += 256) srcsB[base + i] = srt[i];
}

// ---------------------------------------------------------------------------
__device__ __forceinline__ unsigned short f2bf(float f) {   // RTN f32 -> bf16
    unsigned u = __float_as_uint(f);
    unsigned r = u + 0x7FFFu + ((u >> 16) & 1u);
    return (unsigned short)(r >> 16);
}
__device__ __forceinline__ __half2 u2h(unsigned w) {
    union { unsigned u; __half2 h; } c; c.u = w; return c.h;
}
__device__ __forceinline__ unsigned h2u(__half2 h) {
    union { unsigned u; __half2 h; } c; c.h = h; return c.u;
}

// t0 = dis .* (X @ W^T), f16, row stride 40 (80 B). One wave per 16 nodes.
// MFMA on bf16 inputs (f32 accumulate), output stored f16.
__global__ __launch_bounds__(256) void transform_mfma(
    const float* __restrict__ x, const float* __restrict__ W,
    const float* __restrict__ dis, unsigned short* __restrict__ t0, int N)
{
    __shared__ uint4 Wl[3 * 4 * 64];        // B frags, bf16-packed: 12 KiB
    int t = threadIdx.x;
    for (int i = t; i < 3 * 4 * 64; i += 256) {
        int lane = i & 63;
        int kc = (i >> 6) & 3;
        int nt = i >> 8;
        int n = nt * 16 + (lane & 15);
        int k = kc * 32 + (lane >> 4) * 8;
        union { unsigned short s[8]; uint4 v; } u;
        #pragma unroll
        for (int j = 0; j < 8; ++j)
            u.s[j] = (n < N_CLASS) ? f2bf(W[n * N_FEAT + k + j]) : (unsigned short)0;
        Wl[i] = u.v;
    }
    __syncthreads();
    int wave = (blockIdx.x * blockDim.x + threadIdx.x) >> 6;
    int lane = threadIdx.x & 63;
    int ntile = (N + 15) / 16;
    if (wave >= ntile) return;
    int m = lane & 15, quad = lane >> 4;
    int row = wave * 16 + m;
    const short8* Wf = reinterpret_cast<const short8*>(Wl);
    floatx4 acc0 = {0.f, 0.f, 0.f, 0.f}, acc1 = acc0, acc2 = acc0;
    #pragma unroll
    for (int kc = 0; kc < 4; ++kc) {
        const float4* xr = reinterpret_cast<const float4*>(
            x + (size_t)row * N_FEAT + kc * 32 + quad * 8);
        float4 a0 = xr[0], a1 = xr[1];
        short8 af;
        af[0] = f2bf(a0.x); af[1] = f2bf(a0.y); af[2] = f2bf(a0.z); af[3] = f2bf(a0.w);
        af[4] = f2bf(a1.x); af[5] = f2bf(a1.y); af[6] = f2bf(a1.z); af[7] = f2bf(a1.w);
        short8 b0 = Wf[(0 * 4 + kc) * 64 + lane];
        short8 b1 = Wf[(1 * 4 + kc) * 64 + lane];
        short8 b2 = Wf[(2 * 4 + kc) * 64 + lane];
        acc0 = __builtin_amdgcn_mfma_f32_16x16x32_bf16(af, b0, acc0, 0, 0, 0);
        acc1 = __builtin_amdgcn_mfma_f32_16x16x32_bf16(af, b1, acc1, 0, 0, 0);
        acc2 = __builtin_amdgcn_mfma_f32_16x16x32_bf16(af, b2, acc2, 0, 0, 0);
    }
    #pragma unroll
    for (int r = 0; r < 4; ++r) {
        int rw = wave * 16 + quad * 4 + r;
        float ds = dis[rw];
        unsigned short* tr = t0 + (size_t)rw * N_CLASS;
        tr[m] = __half_as_ushort(__float2half(ds * acc0[r]));
        tr[16 + m] = __half_as_ushort(__float2half(ds * acc1[r]));
        if (m < 8) tr[32 + m] = __half_as_ushort(__float2half(ds * acc2[r]));
    }
}

// ---------------------------------------------------------------------------
// Group-per-node gather: 12 groups x 5 lanes per wave; lane sl owns bytes
// [16*sl, 16*sl+16) of the 80 B row. f32 accumulation in two banks.
struct F8 { float v0, v1, v2, v3, v4, v5, v6, v7; };

__device__ __forceinline__ void acc8(F8& a, uint4 r) {
    float2 f0 = __half22float2(u2h(r.x));
    float2 f1 = __half22float2(u2h(r.y));
    float2 f2 = __half22float2(u2h(r.z));
    float2 f3 = __half22float2(u2h(r.w));
    a.v0 += f0.x; a.v1 += f0.y; a.v2 += f1.x; a.v3 += f1.y;
    a.v4 += f2.x; a.v5 += f2.y; a.v6 += f3.x; a.v7 += f3.y;
}
__device__ __forceinline__ void acc8u(F8& a, uintx4 r) {
    uint4 q; q.x = r.x; q.y = r.y; q.z = r.z; q.w = r.w;
    acc8(a, q);
}

// Shared gather over edge range [eBp[d], eEp[d]). SELFH=1: add self row when
// d in half0 (pass 0); SELFH=0: when d in half1 (pass 1) -- keeps every
// table access inside the pass's L2-resident half. srcsB holds byte offsets.
// Table gathers are CACHEABLE; the srcsB offset stream is NONTEMPORAL so it
// does not evict the resident table half. Ghost lanes 60-63 shadow group 11.
#define GATHERG(tin, eBp, eEp, SELFH)                                          \
    int wv = (blockIdx.x * blockDim.x + threadIdx.x) >> 6;                     \
    int lane = threadIdx.x & 63;                                               \
    int g = lane / 5;                                                          \
    int sl = lane - g * 5;                                                     \
    if (g > 11) { g = 11; sl = 0; }                                            \
    int d = wv * 12 + g;                                                       \
    int act = (lane < 60) && (d < N);                                          \
    int dc = min(d, N - 1);                                                    \
    int e0 = (eBp)[dc];                                                        \
    int e1 = (eEp)[dc];                                                        \
    if (d >= N) e1 = e0;                                                       \
    int slo = sl << 4;                                                         \
    const char* tbs = (const char*)(tin) + slo;                                \
    F8 A = {0,0,0,0,0,0,0,0}, B = {0,0,0,0,0,0,0,0};                           \
    if ((SELFH) ? (dc < HALF_SPLIT) : (dc >= HALF_SPLIT)) {                    \
        uint4 rs = *reinterpret_cast<const uint4*>(tbs + (size_t)dc * 80);     \
        acc8(A, rs);                            /* self term row d */          \
    }                                                                          \
    int e = e0;                                                                \
    int ea = min(e1, (e0 + 3) & ~3);                                           \
    for (; e < ea; ++e) {                       /* align to 16 B */            \
        unsigned o = (unsigned)srcsB[e];                                       \
        uint4 r = *reinterpret_cast<const uint4*>(tbs + o);                    \
        acc8(A, r);                                                            \
    }                                                                          \
    for (; e + 4 <= e1; e += 4) {               /* 4 gathers in flight */      \
        intx4 o4 = __builtin_nontemporal_load(                                 \
            reinterpret_cast<const intx4*>(srcsB + e));                        \
        uint4 r0 = *reinterpret_cast<const uint4*>(tbs + (unsigned)o4.x);      \
        uint4 r1 = *reinterpret_cast<const uint4*>(tbs + (unsigned)o4.y);      \
        uint4 r2 = *reinterpret_cast<const uint4*>(tbs + (unsigned)o4.z);      \
        uint4 r3 = *reinterpret_cast<const uint4*>(tbs + (unsigned)o4.w);      \
        acc8(A, r0); acc8(B, r1); acc8(A, r2); acc8(B, r3);                    \
    }                                                                          \
    for (; e < e1; ++e) {                       /* tail <= 3 edges */          \
        unsigned o = (unsigned)srcsB[e];                                       \
        uint4 r = *reinterpret_cast<const uint4*>(tbs + o);                    \
        acc8(A, r);                                                            \
    }                                                                          \
    A.v0 += B.v0; A.v1 += B.v1; A.v2 += B.v2; A.v3 += B.v3;                    \
    A.v4 += B.v4; A.v5 += B.v5; A.v6 += B.v6; A.v7 += B.v7;

// Middle hop, pass 0 (src < HALF): tout[d] = raw f16 partial sums (NT store).
__global__ __launch_bounds__(256) void prop_hop0(
    const unsigned short* __restrict__ tin, unsigned short* __restrict__ tout,
    const int* __restrict__ starts, const int* __restrict__ mid,
    const int* __restrict__ srcsB, int N)
{
    GATHERG(tin, starts, mid, 1)
    if (act) {
        uintx4 o;
        o.x = h2u(__floats2half2_rn(A.v0, A.v1));
        o.y = h2u(__floats2half2_rn(A.v2, A.v3));
        o.z = h2u(__floats2half2_rn(A.v4, A.v5));
        o.w = h2u(__floats2half2_rn(A.v6, A.v7));
        __builtin_nontemporal_store(o,
            reinterpret_cast<uintx4*>((char*)tout + (size_t)d * 80 + slo));
    }
}

// Middle hop, pass 1 (src >= HALF): tout[d] = f16( dd^2 * (partial + sum) ).
__global__ __launch_bounds__(256) void prop_hop1(
    const unsigned short* __restrict__ tin, unsigned short* __restrict__ tout,
    const int* __restrict__ starts, const int* __restrict__ mid,
    const int* __restrict__ srcsB, const float* __restrict__ dis, int N)
{
    GATHERG(tin, mid, starts + 1, 0)
    if (act) {
        uintx4 pr = __builtin_nontemporal_load(
            reinterpret_cast<const uintx4*>((const char*)tout + (size_t)d * 80 + slo));
        acc8u(A, pr);
        float dd = dis[dc];
        float sc = dd * dd;
        uintx4 o;
        o.x = h2u(__floats2half2_rn(sc * A.v0, sc * A.v1));
        o.y = h2u(__floats2half2_rn(sc * A.v2, sc * A.v3));
        o.z = h2u(__floats2half2_rn(sc * A.v4, sc * A.v5));
        o.w = h2u(__floats2half2_rn(sc * A.v6, sc * A.v7));
        __builtin_nontemporal_store(o,
            reinterpret_cast<uintx4*>((char*)tout + (size_t)d * 80 + slo));
    }
}

// Final hop, pass 0: out[d][*] = raw f32 partial (t[d] + sum over half0).
__global__ __launch_bounds__(256) void prop_fin0(
    const unsigned short* __restrict__ tin, float* __restrict__ out,
    const int* __restrict__ starts, const int* __restrict__ mid,
    const int* __restrict__ srcsB, int N)
{
    GATHERG(tin, starts, mid, 1)
    if (act) {
        float* ro = out + (size_t)d * N_CLASS + sl * 8;
        floatx4 lo = {A.v0, A.v1, A.v2, A.v3};
        floatx4 hi = {A.v4, A.v5, A.v6, A.v7};
        __builtin_nontemporal_store(lo, reinterpret_cast<floatx4*>(ro));
        __builtin_nontemporal_store(hi, reinterpret_cast<floatx4*>(ro) + 1);
    }
}

// Final hop, pass 1: sum over half1 + partial, bias + log_softmax.
// Softmax reduce = 4 rotate-shfls within the 5-lane group (12 nodes/wave).
__global__ __launch_bounds__(256) void prop_fin1(
    const unsigned short* __restrict__ tin, float* __restrict__ out,
    const int* __restrict__ starts, const int* __restrict__ mid,
    const int* __restrict__ srcsB, const float* __restrict__ dis,
    const float* __restrict__ bias, int N)
{
    GATHERG(tin, mid, starts + 1, 0)
    float dd = dis[dc];
    const float* pp = out + (size_t)dc * N_CLASS + sl * 8;
    floatx4 plo = __builtin_nontemporal_load(reinterpret_cast<const floatx4*>(pp));
    floatx4 phi = __builtin_nontemporal_load(reinterpret_cast<const floatx4*>(pp) + 1);
    float4 blo = reinterpret_cast<const float4*>(bias)[sl * 2];       // sl<5
    float4 bhi = reinterpret_cast<const float4*>(bias)[sl * 2 + 1];
    float v0 = dd * (plo.x + A.v0) + blo.x, v1 = dd * (plo.y + A.v1) + blo.y;
    float v2 = dd * (plo.z + A.v2) + blo.z, v3 = dd * (plo.w + A.v3) + blo.w;
    float v4 = dd * (phi.x + A.v4) + bhi.x, v5 = dd * (phi.y + A.v5) + bhi.y;
    float v6 = dd * (phi.z + A.v6) + bhi.z, v7 = dd * (phi.w + A.v7) + bhi.w;
    float mx = fmaxf(fmaxf(fmaxf(v0, v1), fmaxf(v2, v3)),
                     fmaxf(fmaxf(v4, v5), fmaxf(v6, v7)));
    int rot = g * 5 + ((sl + 1 == 5) ? 0 : sl + 1);     // next lane in group
    float tmx = mx;
    #pragma unroll
    for (int k = 0; k < 4; ++k) { tmx = __shfl(tmx, rot); mx = fmaxf(mx, tmx); }
    float s = expf(v0 - mx) + expf(v1 - mx) + expf(v2 - mx) + expf(v3 - mx)
            + expf(v4 - mx) + expf(v5 - mx) + expf(v6 - mx) + expf(v7 - mx);
    float ts = s;
    #pragma unroll
    for (int k = 0; k < 4; ++k) { ts = __shfl(ts, rot); s += ts; }
    if (act) {
        float ls = mx + logf(s);
        float* ro = out + (size_t)d * N_CLASS + sl * 8;
        floatx4 lo = {v0 - ls, v1 - ls, v2 - ls, v3 - ls};
        floatx4 hi = {v4 - ls, v5 - ls, v6 - ls, v7 - ls};
        __builtin_nontemporal_store(lo, reinterpret_cast<floatx4*>(ro));
        __builtin_nontemporal_store(hi, reinterpret_cast<floatx4*>(ro) + 1);
    }
}

// ---------------------------------------------------------------------------
extern "C" void kernel_launch(void* const* d_in, const int* in_sizes, int n_in,
                              void* d_out, int out_size, void* d_ws, size_t ws_size,
                              hipStream_t stream) {
    const float* feature = (const float*)d_in[0];   // [N, 128]
    const float* weight  = (const float*)d_in[1];   // [40, 128]
    const float* bias    = (const float*)d_in[2];   // [40]
    const int*   ei      = (const int*)d_in[3];     // [2, E] (int32 or int64 words)
    const int N = N_NODES;
    const int E = in_sizes[3] / 2;

    size_t off = 0;
    auto take = [&](size_t bytes) { size_t o = off; off += (bytes + 255) & ~(size_t)255; return o; };
    char* ws = (char*)d_ws;
    int*   flag      = (int*)  (ws + take(4));
    int*   bCount    = (int*)  (ws + take((size_t)NBALLOC * 4));
    int*   bStart    = (int*)  (ws + take((size_t)(NBALLOC + 1) * 4));
    int*   starts    = (int*)  (ws + take((size_t)(N + 1) * 4));
    int*   mid       = (int*)  (ws + take((size_t)N * 4));
    float* dis       = (float*)(ws + take((size_t)N * 4));
    int*   srcsB     = (int*)  (ws + take((size_t)E * 4));
    // t0+t1 (16 MB contiguous) also host tmp (per-bucket record regions,
    // NBUSED*CAP*4 = 13.6 MB; tmp dead once p4 finishes, before transform)
    unsigned short* t0 = (unsigned short*)(ws + take((size_t)N * N_CLASS * 2));
    unsigned short* t1 = (unsigned short*)(ws + take((size_t)N * N_CLASS * 2));
    unsigned int* tmp = (unsigned int*)t0;

    // --- build CSR (single-level fine bucketed counting sort) ---
    detect_zero_kernel<<<1, 512, 0, stream>>>(ei, flag, bCount);
    const int p3grid = (E + P3BLK - 1) / P3BLK;
    p3a_scatter<<<p3grid, 256, 0, stream>>>(ei, E, flag, bCount, tmp);
    p2_scan<<<1, NBALLOC, 0, stream>>>(bCount, bStart, starts, E);
    p4_sort<<<NBUSED, 256, 0, stream>>>(tmp, bStart, starts, mid, dis, srcsB, N);

    // --- transform (MFMA, pre-scaled f16 rows) then 2 hops x 2 src-passes ---
    const int ntile = (N + 15) / 16;
    const int tblocks = (ntile * 64 + 255) / 256;
    transform_mfma<<<tblocks, 256, 0, stream>>>(feature, weight, dis, t0, N);
    const int nwaves = (N + 11) / 12;                     // 12 nodes per wave
    const int nodeBlocks = (nwaves * 64 + 255) / 256;
    prop_hop0<<<nodeBlocks, 256, 0, stream>>>(t0, t1, starts, mid, srcsB, N);
    prop_hop1<<<nodeBlocks, 256, 0, stream>>>(t0, t1, starts, mid, srcsB, dis, N);
    prop_fin0<<<nodeBlocks, 256, 0, stream>>>(t1, (float*)d_out, starts, mid, srcsB, N);
    prop_fin1<<<nodeBlocks, 256, 0, stream>>>(t1, (float*)d_out, starts, mid, srcsB,
                                              dis, bias, N);
}

// Round 11
// 305.633 us; speedup vs baseline: 1.0855x; 1.0855x over previous
//
#include <hip/hip_runtime.h>
#include <hip/hip_bf16.h>
#include <hip/hip_fp16.h>
#include <math.h>

// SGC: out = log_softmax( S^2 X W^T + b ), S = D^-1/2 (A+I) D^-1/2
// t0 = dis .* (X W^T) in *f16* (pre-scaled 80 B rows).
// Props (r5/r7, proven): src-range pass split (each pass gathers one 4 MB
// table half -> L2-resident) x group-per-node gather (5-lane group per dst,
// 12 nodes/wave, f32 accum, no folds). r10 lesson: NO nontemporal hints on
// anything that is re-read (hop1's t1 output IS the fin gather table; NT
// there cost +19 us). Only fin1's final store is NT (truly dead).
// CSR build: r7 block-local LDS counting sort (P3BLK=6250, measured optimum;
// r8 occupancy and r9 rotation probes were null -> r7 form kept).
// NEW (round 11): two serialization bubbles removed --
//   detect_zero folded into p3a (per-block is64 ballot) + hipMemsetAsync;
//   p2_scan folded into p4 (each block scans the 512 bucket counts in LDS).
// 9 dispatches -> 8, two 1-block kernel boundaries off the critical path.

#define N_NODES 100000
#define N_FEAT  128
#define N_CLASS 40

#define RANGE   256           // dsts per fine bucket (pow2: dst>>8)
#define NBALLOC 512
#define NBUSED  391           // ceil(100000/256)
#define CAP     8704          // fine bucket cap (mean 8192 + ~5.7 sigma)
#define P3BLK   6250          // edges per p3a block (grid = ceil(E/P3BLK))
#define HALF_SPLIT 50000      // src-range split point (table half = 4 MB)

typedef __attribute__((ext_vector_type(8))) short short8;   // 8 bf16 (4 VGPRs)
typedef __attribute__((ext_vector_type(4))) float floatx4;  // f32x4 (NT-able)

__device__ __forceinline__ int edge_word(const int* ei, int elem, int is64) {
    return is64 ? ei[2 * elem] : ei[elem];
}

// P3a: per-block is64 detect (ballot over first 64 odd words), then
// block-local LDS counting sort over 512 fine buckets, then coalesced
// bucket-grouped run writes into fixed-stride regions tmp[f*CAP + p].
// bucketCount (pre-zeroed by memset) accumulates global per-bucket totals.
__global__ __launch_bounds__(256) void p3a_scatter(
    const int* __restrict__ ei, int E,
    int* __restrict__ bucketCount, unsigned int* __restrict__ tmp)
{
    __shared__ unsigned int srt[P3BLK];     // bucket-grouped records
    __shared__ unsigned short fb[P3BLK];    // bucket id per record
    __shared__ int hist[NBALLOC];
    __shared__ int lbase[NBALLOC];          // block-local exclusive scan
    __shared__ int gbase[NBALLOC];          // global run base per bucket
    __shared__ int cur[NBALLOC];
    __shared__ int sc[256];
    __shared__ int s_is64;
    int t = threadIdx.x;
    for (int i = t; i < NBALLOC; i += 256) hist[i] = 0;
    if (t < 64) {                            // wave 0: int32/int64 detect
        int nz = (ei[2 * t + 1] != 0) ? 1 : 0;
        unsigned long long bl = __ballot(nz);
        if (t == 0) s_is64 = (bl == 0ull) ? 1 : 0;
    }
    __syncthreads();
    int is64 = s_is64;
    int per = (E + gridDim.x - 1) / gridDim.x;
    int e0 = blockIdx.x * per;
    int e1 = min(E, e0 + per);
    int n = e1 - e0;
    for (int e = e0 + t; e < e1; e += 256) {
        int c = edge_word(ei, E + e, is64);
        atomicAdd(&hist[c >> 8], 1);
    }
    __syncthreads();
    int h0 = hist[2 * t], h1 = hist[2 * t + 1];
    sc[t] = h0 + h1;
    __syncthreads();
    for (int o = 1; o < 256; o <<= 1) {
        int y = (t >= o) ? sc[t - o] : 0;
        __syncthreads();
        sc[t] += y;
        __syncthreads();
    }
    int excl = sc[t] - (h0 + h1);
    lbase[2 * t] = excl;
    lbase[2 * t + 1] = excl + h0;
    cur[2 * t] = excl;
    cur[2 * t + 1] = excl + h0;
    gbase[2 * t]     = h0 ? atomicAdd(&bucketCount[2 * t], h0) : 0;
    gbase[2 * t + 1] = h1 ? atomicAdd(&bucketCount[2 * t + 1], h1) : 0;
    __syncthreads();
    for (int e = e0 + t; e < e1; e += 256) {
        int c = edge_word(ei, E + e, is64);
        int r = edge_word(ei, e, is64);
        int f = c >> 8;
        int p = atomicAdd(&cur[f], 1);
        srt[p] = ((unsigned)(c & 255) << 24) | (unsigned)r;
        fb[p] = (unsigned short)f;
    }
    __syncthreads();
    for (int i = t; i < n; i += 256) {
        int f = fb[i];
        int p = gbase[f] + (i - lbase[f]);
        if (p < CAP) tmp[(size_t)f * CAP + p] = srt[i];
    }
}

// P4: global scan of bucketCount in-block (p2 folded in) -> base; then
// per-fine-bucket LDS counting sort with 512 keys (dlf*2 + srcHalf) ->
// starts, mid (end of half0 / begin of half1), dis, srcsB (byte offsets,
// src*80, coalesced). Records come from tmp[b*CAP + i] (region-stride).
__global__ __launch_bounds__(256) void p4_sort(
    const unsigned int* __restrict__ tmp, const int* __restrict__ bucketCount,
    int* __restrict__ starts, int* __restrict__ mid, float* __restrict__ dis,
    int* __restrict__ srcsB, int N, int E)
{
    __shared__ int srt[CAP];
    __shared__ int hist[512];
    __shared__ int sc[256];
    __shared__ int cur[512];
    __shared__ int cnt[NBALLOC];
    __shared__ int base_s;
    int b = blockIdx.x, t = threadIdx.x;
    int g0 = b * RANGE;
    int gcnt = N - g0;
    if (gcnt > RANGE) gcnt = RANGE;
    // --- folded p2: scan the 512 global bucket counts for this block's base
    for (int i = t; i < NBALLOC; i += 256) cnt[i] = bucketCount[i];
    __syncthreads();
    int p0 = cnt[2 * t], p1 = cnt[2 * t + 1];
    sc[t] = p0 + p1;
    __syncthreads();
    for (int o = 1; o < 256; o <<= 1) {
        int y = (t >= o) ? sc[t - o] : 0;
        __syncthreads();
        sc[t] += y;
        __syncthreads();
    }
    if (t == 0) {
        int pairs = b >> 1;
        int base = (pairs > 0) ? sc[pairs - 1] : 0;
        if (b & 1) base += cnt[b - 1];
        base_s = base;
        if (b == 0) starts[N_NODES] = E;
    }
    __syncthreads();
    int base = base_s;
    int n = cnt[b];
    int nr = min(n, CAP);                       // records actually present
    const unsigned int* rec = tmp + (size_t)b * CAP;
    hist[t] = 0;
    hist[t + 256] = 0;
    __syncthreads();
    for (int i = t; i < nr; i += 256) {
        unsigned v = rec[i];
        int key = (int)((v >> 24) << 1) | (((v & 0xFFFFFFu) >= HALF_SPLIT) ? 1 : 0);
        atomicAdd(&hist[key], 1);
    }
    __syncthreads();
    int c0 = hist[2 * t], c1 = hist[2 * t + 1];
    sc[t] = c0 + c1;
    __syncthreads();
    for (int o = 1; o < 256; o <<= 1) {
        int y = (t >= o) ? sc[t - o] : 0;
        __syncthreads();
        sc[t] += y;
        __syncthreads();
    }
    int excl = sc[t] - (c0 + c1);
    if (t < gcnt) {
        starts[g0 + t] = base + excl;
        mid[g0 + t] = base + excl + c0;
        dis[g0 + t] = rsqrtf((float)(c0 + c1 + 1));   // +1 self-loop
    }
    cur[2 * t] = excl;
    cur[2 * t + 1] = excl + c0;
    __syncthreads();
    for (int i = t; i < nr; i += 256) {
        unsigned v = rec[i];
        int src = (int)(v & 0xFFFFFFu);
        int key = (int)((v >> 24) << 1) | ((src >= HALF_SPLIT) ? 1 : 0);
        int p = atomicAdd(&cur[key], 1);
        srt[p] = src * 80;                       // pre-scaled byte offset
    }
    __syncthreads();
    for (int i = t; i < nr; i += 256) srcsB[base + i] = srt[i];
}

// ---------------------------------------------------------------------------
__device__ __forceinline__ unsigned short f2bf(float f) {   // RTN f32 -> bf16
    unsigned u = __float_as_uint(f);
    unsigned r = u + 0x7FFFu + ((u >> 16) & 1u);
    return (unsigned short)(r >> 16);
}
__device__ __forceinline__ __half2 u2h(unsigned w) {
    union { unsigned u; __half2 h; } c; c.u = w; return c.h;
}
__device__ __forceinline__ unsigned h2u(__half2 h) {
    union { unsigned u; __half2 h; } c; c.h = h; return c.u;
}

// t0 = dis .* (X @ W^T), f16, row stride 40 (80 B). One wave per 16 nodes.
// MFMA on bf16 inputs (f32 accumulate), output stored f16.
__global__ __launch_bounds__(256) void transform_mfma(
    const float* __restrict__ x, const float* __restrict__ W,
    const float* __restrict__ dis, unsigned short* __restrict__ t0, int N)
{
    __shared__ uint4 Wl[3 * 4 * 64];        // B frags, bf16-packed: 12 KiB
    int t = threadIdx.x;
    for (int i = t; i < 3 * 4 * 64; i += 256) {
        int lane = i & 63;
        int kc = (i >> 6) & 3;
        int nt = i >> 8;
        int n = nt * 16 + (lane & 15);
        int k = kc * 32 + (lane >> 4) * 8;
        union { unsigned short s[8]; uint4 v; } u;
        #pragma unroll
        for (int j = 0; j < 8; ++j)
            u.s[j] = (n < N_CLASS) ? f2bf(W[n * N_FEAT + k + j]) : (unsigned short)0;
        Wl[i] = u.v;
    }
    __syncthreads();
    int wave = (blockIdx.x * blockDim.x + threadIdx.x) >> 6;
    int lane = threadIdx.x & 63;
    int ntile = (N + 15) / 16;
    if (wave >= ntile) return;
    int m = lane & 15, quad = lane >> 4;
    int row = wave * 16 + m;
    const short8* Wf = reinterpret_cast<const short8*>(Wl);
    floatx4 acc0 = {0.f, 0.f, 0.f, 0.f}, acc1 = acc0, acc2 = acc0;
    #pragma unroll
    for (int kc = 0; kc < 4; ++kc) {
        const float4* xr = reinterpret_cast<const float4*>(
            x + (size_t)row * N_FEAT + kc * 32 + quad * 8);
        float4 a0 = xr[0], a1 = xr[1];
        short8 af;
        af[0] = f2bf(a0.x); af[1] = f2bf(a0.y); af[2] = f2bf(a0.z); af[3] = f2bf(a0.w);
        af[4] = f2bf(a1.x); af[5] = f2bf(a1.y); af[6] = f2bf(a1.z); af[7] = f2bf(a1.w);
        short8 b0 = Wf[(0 * 4 + kc) * 64 + lane];
        short8 b1 = Wf[(1 * 4 + kc) * 64 + lane];
        short8 b2 = Wf[(2 * 4 + kc) * 64 + lane];
        acc0 = __builtin_amdgcn_mfma_f32_16x16x32_bf16(af, b0, acc0, 0, 0, 0);
        acc1 = __builtin_amdgcn_mfma_f32_16x16x32_bf16(af, b1, acc1, 0, 0, 0);
        acc2 = __builtin_amdgcn_mfma_f32_16x16x32_bf16(af, b2, acc2, 0, 0, 0);
    }
    #pragma unroll
    for (int r = 0; r < 4; ++r) {
        int rw = wave * 16 + quad * 4 + r;
        float ds = dis[rw];
        unsigned short* tr = t0 + (size_t)rw * N_CLASS;
        tr[m] = __half_as_ushort(__float2half(ds * acc0[r]));
        tr[16 + m] = __half_as_ushort(__float2half(ds * acc1[r]));
        if (m < 8) tr[32 + m] = __half_as_ushort(__float2half(ds * acc2[r]));
    }
}

// ---------------------------------------------------------------------------
// Group-per-node gather: 12 groups x 5 lanes per wave; lane sl owns bytes
// [16*sl, 16*sl+16) of the 80 B row. f32 accumulation in two banks.
struct F8 { float v0, v1, v2, v3, v4, v5, v6, v7; };

__device__ __forceinline__ void acc8(F8& a, uint4 r) {
    float2 f0 = __half22float2(u2h(r.x));
    float2 f1 = __half22float2(u2h(r.y));
    float2 f2 = __half22float2(u2h(r.z));
    float2 f3 = __half22float2(u2h(r.w));
    a.v0 += f0.x; a.v1 += f0.y; a.v2 += f1.x; a.v3 += f1.y;
    a.v4 += f2.x; a.v5 += f2.y; a.v6 += f3.x; a.v7 += f3.y;
}

// Shared gather over edge range [eBp[d], eEp[d]). SELFH=1: add self row when
// d in half0 (pass 0); SELFH=0: when d in half1 (pass 1) -- keeps every
// table access inside the pass's L2-resident half. srcsB holds byte offsets.
// Ghost lanes 60-63 shadow group 11 (results discarded via act).
#define GATHERG(tin, eBp, eEp, SELFH)                                          \
    int wv = (blockIdx.x * blockDim.x + threadIdx.x) >> 6;                     \
    int lane = threadIdx.x & 63;                                               \
    int g = lane / 5;                                                          \
    int sl = lane - g * 5;                                                     \
    if (g > 11) { g = 11; sl = 0; }                                            \
    int d = wv * 12 + g;                                                       \
    int act = (lane < 60) && (d < N);                                          \
    int dc = min(d, N - 1);                                                    \
    int e0 = (eBp)[dc];                                                        \
    int e1 = (eEp)[dc];                                                        \
    if (d >= N) e1 = e0;                                                       \
    int slo = sl << 4;                                                         \
    const char* tbs = (const char*)(tin) + slo;                                \
    F8 A = {0,0,0,0,0,0,0,0}, B = {0,0,0,0,0,0,0,0};                           \
    if ((SELFH) ? (dc < HALF_SPLIT) : (dc >= HALF_SPLIT)) {                    \
        uint4 rs = *reinterpret_cast<const uint4*>(tbs + (size_t)dc * 80);     \
        acc8(A, rs);                            /* self term row d */          \
    }                                                                          \
    int e = e0;                                                                \
    int ea = min(e1, (e0 + 3) & ~3);                                           \
    for (; e < ea; ++e) {                       /* align to 16 B */            \
        unsigned o = (unsigned)srcsB[e];                                       \
        uint4 r = *reinterpret_cast<const uint4*>(tbs + o);                    \
        acc8(A, r);                                                            \
    }                                                                          \
    for (; e + 4 <= e1; e += 4) {               /* 4 gathers in flight */      \
        int4 o4 = *reinterpret_cast<const int4*>(srcsB + e);                   \
        uint4 r0 = *reinterpret_cast<const uint4*>(tbs + (unsigned)o4.x);      \
        uint4 r1 = *reinterpret_cast<const uint4*>(tbs + (unsigned)o4.y);      \
        uint4 r2 = *reinterpret_cast<const uint4*>(tbs + (unsigned)o4.z);      \
        uint4 r3 = *reinterpret_cast<const uint4*>(tbs + (unsigned)o4.w);      \
        acc8(A, r0); acc8(B, r1); acc8(A, r2); acc8(B, r3);                    \
    }                                                                          \
    for (; e < e1; ++e) {                       /* tail <= 3 edges */          \
        unsigned o = (unsigned)srcsB[e];                                       \
        uint4 r = *reinterpret_cast<const uint4*>(tbs + o);                    \
        acc8(A, r);                                                            \
    }                                                                          \
    A.v0 += B.v0; A.v1 += B.v1; A.v2 += B.v2; A.v3 += B.v3;                    \
    A.v4 += B.v4; A.v5 += B.v5; A.v6 += B.v6; A.v7 += B.v7;

// Middle hop, pass 0 (src < HALF): tout[d] = raw f16 partial sums.
__global__ __launch_bounds__(256) void prop_hop0(
    const unsigned short* __restrict__ tin, unsigned short* __restrict__ tout,
    const int* __restrict__ starts, const int* __restrict__ mid,
    const int* __restrict__ srcsB, int N)
{
    GATHERG(tin, starts, mid, 1)
    if (act) {
        uint4 o;
        o.x = h2u(__floats2half2_rn(A.v0, A.v1));
        o.y = h2u(__floats2half2_rn(A.v2, A.v3));
        o.z = h2u(__floats2half2_rn(A.v4, A.v5));
        o.w = h2u(__floats2half2_rn(A.v6, A.v7));
        *reinterpret_cast<uint4*>((char*)tout + (size_t)d * 80 + slo) = o;
    }
}

// Middle hop, pass 1 (src >= HALF): tout[d] = f16( dd^2 * (partial + sum) ).
__global__ __launch_bounds__(256) void prop_hop1(
    const unsigned short* __restrict__ tin, unsigned short* __restrict__ tout,
    const int* __restrict__ starts, const int* __restrict__ mid,
    const int* __restrict__ srcsB, const float* __restrict__ dis, int N)
{
    GATHERG(tin, mid, starts + 1, 0)
    if (act) {
        uint4 pr = *reinterpret_cast<const uint4*>((const char*)tout + (size_t)d * 80 + slo);
        acc8(A, pr);
        float dd = dis[dc];
        float sc = dd * dd;
        uint4 o;
        o.x = h2u(__floats2half2_rn(sc * A.v0, sc * A.v1));
        o.y = h2u(__floats2half2_rn(sc * A.v2, sc * A.v3));
        o.z = h2u(__floats2half2_rn(sc * A.v4, sc * A.v5));
        o.w = h2u(__floats2half2_rn(sc * A.v6, sc * A.v7));
        *reinterpret_cast<uint4*>((char*)tout + (size_t)d * 80 + slo) = o;
    }
}

// Final hop, pass 0: out[d][*] = raw f32 partial (t[d] + sum over half0).
__global__ __launch_bounds__(256) void prop_fin0(
    const unsigned short* __restrict__ tin, float* __restrict__ out,
    const int* __restrict__ starts, const int* __restrict__ mid,
    const int* __restrict__ srcsB, int N)
{
    GATHERG(tin, starts, mid, 1)
    if (act) {
        float* ro = out + (size_t)d * N_CLASS + sl * 8;
        *reinterpret_cast<float4*>(ro)     = make_float4(A.v0, A.v1, A.v2, A.v3);
        *reinterpret_cast<float4*>(ro + 4) = make_float4(A.v4, A.v5, A.v6, A.v7);
    }
}

// Final hop, pass 1: sum over half1 + partial, bias + log_softmax.
// Softmax reduce = 4 rotate-shfls within the 5-lane group (12 nodes/wave).
// Final stores are nontemporal (out is never re-read).
__global__ __launch_bounds__(256) void prop_fin1(
    const unsigned short* __restrict__ tin, float* __restrict__ out,
    const int* __restrict__ starts, const int* __restrict__ mid,
    const int* __restrict__ srcsB, const float* __restrict__ dis,
    const float* __restrict__ bias, int N)
{
    GATHERG(tin, mid, starts + 1, 0)
    float dd = dis[dc];
    const float* pp = out + (size_t)dc * N_CLASS + sl * 8;
    float4 plo = *reinterpret_cast<const float4*>(pp);
    float4 phi = *reinterpret_cast<const float4*>(pp + 4);
    float4 blo = reinterpret_cast<const float4*>(bias)[sl * 2];       // sl<5
    float4 bhi = reinterpret_cast<const float4*>(bias)[sl * 2 + 1];
    float v0 = dd * (plo.x + A.v0) + blo.x, v1 = dd * (plo.y + A.v1) + blo.y;
    float v2 = dd * (plo.z + A.v2) + blo.z, v3 = dd * (plo.w + A.v3) + blo.w;
    float v4 = dd * (phi.x + A.v4) + bhi.x, v5 = dd * (phi.y + A.v5) + bhi.y;
    float v6 = dd * (phi.z + A.v6) + bhi.z, v7 = dd * (phi.w + A.v7) + bhi.w;
    float mx = fmaxf(fmaxf(fmaxf(v0, v1), fmaxf(v2, v3)),
                     fmaxf(fmaxf(v4, v5), fmaxf(v6, v7)));
    int rot = g * 5 + ((sl + 1 == 5) ? 0 : sl + 1);     // next lane in group
    float tmx = mx;
    #pragma unroll
    for (int k = 0; k < 4; ++k) { tmx = __shfl(tmx, rot); mx = fmaxf(mx, tmx); }
    float s = expf(v0 - mx) + expf(v1 - mx) + expf(v2 - mx) + expf(v3 - mx)
            + expf(v4 - mx) + expf(v5 - mx) + expf(v6 - mx) + expf(v7 - mx);
    float ts = s;
    #pragma unroll
    for (int k = 0; k < 4; ++k) { ts = __shfl(ts, rot); s += ts; }
    if (act) {
        float ls = mx + logf(s);
        float* ro = out + (size_t)d * N_CLASS + sl * 8;
        floatx4 lo = {v0 - ls, v1 - ls, v2 - ls, v3 - ls};
        floatx4 hi = {v4 - ls, v5 - ls, v6 - ls, v7 - ls};
        __builtin_nontemporal_store(lo, reinterpret_cast<floatx4*>(ro));
        __builtin_nontemporal_store(hi, reinterpret_cast<floatx4*>(ro) + 1);
    }
}

// ---------------------------------------------------------------------------
extern "C" void kernel_launch(void* const* d_in, const int* in_sizes, int n_in,
                              void* d_out, int out_size, void* d_ws, size_t ws_size,
                              hipStream_t stream) {
    const float* feature = (const float*)d_in[0];   // [N, 128]
    const float* weight  = (const float*)d_in[1];   // [40, 128]
    const float* bias    = (const float*)d_in[2];   // [40]
    const int*   ei      = (const int*)d_in[3];     // [2, E] (int32 or int64 words)
    const int N = N_NODES;
    const int E = in_sizes[3] / 2;

    size_t off = 0;
    auto take = [&](size_t bytes) { size_t o = off; off += (bytes + 255) & ~(size_t)255; return o; };
    char* ws = (char*)d_ws;
    int*   bCount    = (int*)  (ws + take((size_t)NBALLOC * 4));
    int*   starts    = (int*)  (ws + take((size_t)(N + 1) * 4));
    int*   mid       = (int*)  (ws + take((size_t)N * 4));
    float* dis       = (float*)(ws + take((size_t)N * 4));
    int*   srcsB     = (int*)  (ws + take((size_t)E * 4));
    // t0+t1 (16 MB contiguous) also host tmp (per-bucket record regions,
    // NBUSED*CAP*4 = 13.6 MB; tmp dead once p4 finishes, before transform)
    unsigned short* t0 = (unsigned short*)(ws + take((size_t)N * N_CLASS * 2));
    unsigned short* t1 = (unsigned short*)(ws + take((size_t)N * N_CLASS * 2));
    unsigned int* tmp = (unsigned int*)t0;

    // --- build CSR (single-level fine bucketed counting sort) ---
    hipMemsetAsync(bCount, 0, (size_t)NBALLOC * 4, stream);
    const int p3grid = (E + P3BLK - 1) / P3BLK;
    p3a_scatter<<<p3grid, 256, 0, stream>>>(ei, E, bCount, tmp);
    p4_sort<<<NBUSED, 256, 0, stream>>>(tmp, bCount, starts, mid, dis, srcsB, N, E);

    // --- transform (MFMA, pre-scaled f16 rows) then 2 hops x 2 src-passes ---
    const int ntile = (N + 15) / 16;
    const int tblocks = (ntile * 64 + 255) / 256;
    transform_mfma<<<tblocks, 256, 0, stream>>>(feature, weight, dis, t0, N);
    const int nwaves = (N + 11) / 12;                     // 12 nodes per wave
    const int nodeBlocks = (nwaves * 64 + 255) / 256;
    prop_hop0<<<nodeBlocks, 256, 0, stream>>>(t0, t1, starts, mid, srcsB, N);
    prop_hop1<<<nodeBlocks, 256, 0, stream>>>(t0, t1, starts, mid, srcsB, dis, N);
    prop_fin0<<<nodeBlocks, 256, 0, stream>>>(t1, (float*)d_out, starts, mid, srcsB, N);
    prop_fin1<<<nodeBlocks, 256, 0, stream>>>(t1, (float*)d_out, starts, mid, srcsB,
                                              dis, bias, N);
}

// Round 12
// 301.437 us; speedup vs baseline: 1.1006x; 1.0139x over previous
//
#include <hip/hip_runtime.h>
#include <hip/hip_bf16.h>
#include <hip/hip_fp16.h>
#include <math.h>

// SGC: out = log_softmax( S^2 X W^T + b ), S = D^-1/2 (A+I) D^-1/2
// t0 = dis .* (X W^T) in *f16* (pre-scaled 80 B rows).
// Props: src-range pass split (each pass gathers one 4 MB table half ->
// L2-resident) x group-per-node gather (5-lane group per dst, 12 nodes/wave,
// f32 accum, no folds). NEW (round 12): gather unroll deepened 4 -> 8 edges
// in flight. Props are MLP-bound (VGPR=20 left pipeline depth on the table);
// 8 gathers/iter doubles loads-in-flight per wave at ~40 VGPR (still full
// occupancy). A/B bank alternation preserved -> bitwise-identical sums.
// r10 lesson kept: NO nontemporal on re-read data; only fin1 final store NT.
// CSR build: r7 block-local LDS counting sort (P3BLK=6250, probes r8/r9
// null) with r11's folds (is64 in p3a, p2 scan in p4). 8 dispatches.

#define N_NODES 100000
#define N_FEAT  128
#define N_CLASS 40

#define RANGE   256           // dsts per fine bucket (pow2: dst>>8)
#define NBALLOC 512
#define NBUSED  391           // ceil(100000/256)
#define CAP     8704          // fine bucket cap (mean 8192 + ~5.7 sigma)
#define P3BLK   6250          // edges per p3a block (grid = ceil(E/P3BLK))
#define HALF_SPLIT 50000      // src-range split point (table half = 4 MB)

typedef __attribute__((ext_vector_type(8))) short short8;   // 8 bf16 (4 VGPRs)
typedef __attribute__((ext_vector_type(4))) float floatx4;  // f32x4 (NT-able)

__device__ __forceinline__ int edge_word(const int* ei, int elem, int is64) {
    return is64 ? ei[2 * elem] : ei[elem];
}

// P3a: per-block is64 detect (ballot over first 64 odd words), then
// block-local LDS counting sort over 512 fine buckets, then coalesced
// bucket-grouped run writes into fixed-stride regions tmp[f*CAP + p].
// bucketCount (pre-zeroed by memset) accumulates global per-bucket totals.
__global__ __launch_bounds__(256) void p3a_scatter(
    const int* __restrict__ ei, int E,
    int* __restrict__ bucketCount, unsigned int* __restrict__ tmp)
{
    __shared__ unsigned int srt[P3BLK];     // bucket-grouped records
    __shared__ unsigned short fb[P3BLK];    // bucket id per record
    __shared__ int hist[NBALLOC];
    __shared__ int lbase[NBALLOC];          // block-local exclusive scan
    __shared__ int gbase[NBALLOC];          // global run base per bucket
    __shared__ int cur[NBALLOC];
    __shared__ int sc[256];
    __shared__ int s_is64;
    int t = threadIdx.x;
    for (int i = t; i < NBALLOC; i += 256) hist[i] = 0;
    if (t < 64) {                            // wave 0: int32/int64 detect
        int nz = (ei[2 * t + 1] != 0) ? 1 : 0;
        unsigned long long bl = __ballot(nz);
        if (t == 0) s_is64 = (bl == 0ull) ? 1 : 0;
    }
    __syncthreads();
    int is64 = s_is64;
    int per = (E + gridDim.x - 1) / gridDim.x;
    int e0 = blockIdx.x * per;
    int e1 = min(E, e0 + per);
    int n = e1 - e0;
    for (int e = e0 + t; e < e1; e += 256) {
        int c = edge_word(ei, E + e, is64);
        atomicAdd(&hist[c >> 8], 1);
    }
    __syncthreads();
    int h0 = hist[2 * t], h1 = hist[2 * t + 1];
    sc[t] = h0 + h1;
    __syncthreads();
    for (int o = 1; o < 256; o <<= 1) {
        int y = (t >= o) ? sc[t - o] : 0;
        __syncthreads();
        sc[t] += y;
        __syncthreads();
    }
    int excl = sc[t] - (h0 + h1);
    lbase[2 * t] = excl;
    lbase[2 * t + 1] = excl + h0;
    cur[2 * t] = excl;
    cur[2 * t + 1] = excl + h0;
    gbase[2 * t]     = h0 ? atomicAdd(&bucketCount[2 * t], h0) : 0;
    gbase[2 * t + 1] = h1 ? atomicAdd(&bucketCount[2 * t + 1], h1) : 0;
    __syncthreads();
    for (int e = e0 + t; e < e1; e += 256) {
        int c = edge_word(ei, E + e, is64);
        int r = edge_word(ei, e, is64);
        int f = c >> 8;
        int p = atomicAdd(&cur[f], 1);
        srt[p] = ((unsigned)(c & 255) << 24) | (unsigned)r;
        fb[p] = (unsigned short)f;
    }
    __syncthreads();
    for (int i = t; i < n; i += 256) {
        int f = fb[i];
        int p = gbase[f] + (i - lbase[f]);
        if (p < CAP) tmp[(size_t)f * CAP + p] = srt[i];
    }
}

// P4: global scan of bucketCount in-block (p2 folded in) -> base; then
// per-fine-bucket LDS counting sort with 512 keys (dlf*2 + srcHalf) ->
// starts, mid (end of half0 / begin of half1), dis, srcsB (byte offsets,
// src*80, coalesced). Records come from tmp[b*CAP + i] (region-stride).
__global__ __launch_bounds__(256) void p4_sort(
    const unsigned int* __restrict__ tmp, const int* __restrict__ bucketCount,
    int* __restrict__ starts, int* __restrict__ mid, float* __restrict__ dis,
    int* __restrict__ srcsB, int N, int E)
{
    __shared__ int srt[CAP];
    __shared__ int hist[512];
    __shared__ int sc[256];
    __shared__ int cur[512];
    __shared__ int cnt[NBALLOC];
    __shared__ int base_s;
    int b = blockIdx.x, t = threadIdx.x;
    int g0 = b * RANGE;
    int gcnt = N - g0;
    if (gcnt > RANGE) gcnt = RANGE;
    // --- folded p2: scan the 512 global bucket counts for this block's base
    for (int i = t; i < NBALLOC; i += 256) cnt[i] = bucketCount[i];
    __syncthreads();
    int p0 = cnt[2 * t], p1 = cnt[2 * t + 1];
    sc[t] = p0 + p1;
    __syncthreads();
    for (int o = 1; o < 256; o <<= 1) {
        int y = (t >= o) ? sc[t - o] : 0;
        __syncthreads();
        sc[t] += y;
        __syncthreads();
    }
    if (t == 0) {
        int pairs = b >> 1;
        int base = (pairs > 0) ? sc[pairs - 1] : 0;
        if (b & 1) base += cnt[b - 1];
        base_s = base;
        if (b == 0) starts[N_NODES] = E;
    }
    __syncthreads();
    int base = base_s;
    int n = cnt[b];
    int nr = min(n, CAP);                       // records actually present
    const unsigned int* rec = tmp + (size_t)b * CAP;
    hist[t] = 0;
    hist[t + 256] = 0;
    __syncthreads();
    for (int i = t; i < nr; i += 256) {
        unsigned v = rec[i];
        int key = (int)((v >> 24) << 1) | (((v & 0xFFFFFFu) >= HALF_SPLIT) ? 1 : 0);
        atomicAdd(&hist[key], 1);
    }
    __syncthreads();
    int c0 = hist[2 * t], c1 = hist[2 * t + 1];
    sc[t] = c0 + c1;
    __syncthreads();
    for (int o = 1; o < 256; o <<= 1) {
        int y = (t >= o) ? sc[t - o] : 0;
        __syncthreads();
        sc[t] += y;
        __syncthreads();
    }
    int excl = sc[t] - (c0 + c1);
    if (t < gcnt) {
        starts[g0 + t] = base + excl;
        mid[g0 + t] = base + excl + c0;
        dis[g0 + t] = rsqrtf((float)(c0 + c1 + 1));   // +1 self-loop
    }
    cur[2 * t] = excl;
    cur[2 * t + 1] = excl + c0;
    __syncthreads();
    for (int i = t; i < nr; i += 256) {
        unsigned v = rec[i];
        int src = (int)(v & 0xFFFFFFu);
        int key = (int)((v >> 24) << 1) | ((src >= HALF_SPLIT) ? 1 : 0);
        int p = atomicAdd(&cur[key], 1);
        srt[p] = src * 80;                       // pre-scaled byte offset
    }
    __syncthreads();
    for (int i = t; i < nr; i += 256) srcsB[base + i] = srt[i];
}

// ---------------------------------------------------------------------------
__device__ __forceinline__ unsigned short f2bf(float f) {   // RTN f32 -> bf16
    unsigned u = __float_as_uint(f);
    unsigned r = u + 0x7FFFu + ((u >> 16) & 1u);
    return (unsigned short)(r >> 16);
}
__device__ __forceinline__ __half2 u2h(unsigned w) {
    union { unsigned u; __half2 h; } c; c.u = w; return c.h;
}
__device__ __forceinline__ unsigned h2u(__half2 h) {
    union { unsigned u; __half2 h; } c; c.h = h; return c.u;
}

// t0 = dis .* (X @ W^T), f16, row stride 40 (80 B). One wave per 16 nodes.
// MFMA on bf16 inputs (f32 accumulate), output stored f16.
__global__ __launch_bounds__(256) void transform_mfma(
    const float* __restrict__ x, const float* __restrict__ W,
    const float* __restrict__ dis, unsigned short* __restrict__ t0, int N)
{
    __shared__ uint4 Wl[3 * 4 * 64];        // B frags, bf16-packed: 12 KiB
    int t = threadIdx.x;
    for (int i = t; i < 3 * 4 * 64; i += 256) {
        int lane = i & 63;
        int kc = (i >> 6) & 3;
        int nt = i >> 8;
        int n = nt * 16 + (lane & 15);
        int k = kc * 32 + (lane >> 4) * 8;
        union { unsigned short s[8]; uint4 v; } u;
        #pragma unroll
        for (int j = 0; j < 8; ++j)
            u.s[j] = (n < N_CLASS) ? f2bf(W[n * N_FEAT + k + j]) : (unsigned short)0;
        Wl[i] = u.v;
    }
    __syncthreads();
    int wave = (blockIdx.x * blockDim.x + threadIdx.x) >> 6;
    int lane = threadIdx.x & 63;
    int ntile = (N + 15) / 16;
    if (wave >= ntile) return;
    int m = lane & 15, quad = lane >> 4;
    int row = wave * 16 + m;
    const short8* Wf = reinterpret_cast<const short8*>(Wl);
    floatx4 acc0 = {0.f, 0.f, 0.f, 0.f}, acc1 = acc0, acc2 = acc0;
    #pragma unroll
    for (int kc = 0; kc < 4; ++kc) {
        const float4* xr = reinterpret_cast<const float4*>(
            x + (size_t)row * N_FEAT + kc * 32 + quad * 8);
        float4 a0 = xr[0], a1 = xr[1];
        short8 af;
        af[0] = f2bf(a0.x); af[1] = f2bf(a0.y); af[2] = f2bf(a0.z); af[3] = f2bf(a0.w);
        af[4] = f2bf(a1.x); af[5] = f2bf(a1.y); af[6] = f2bf(a1.z); af[7] = f2bf(a1.w);
        short8 b0 = Wf[(0 * 4 + kc) * 64 + lane];
        short8 b1 = Wf[(1 * 4 + kc) * 64 + lane];
        short8 b2 = Wf[(2 * 4 + kc) * 64 + lane];
        acc0 = __builtin_amdgcn_mfma_f32_16x16x32_bf16(af, b0, acc0, 0, 0, 0);
        acc1 = __builtin_amdgcn_mfma_f32_16x16x32_bf16(af, b1, acc1, 0, 0, 0);
        acc2 = __builtin_amdgcn_mfma_f32_16x16x32_bf16(af, b2, acc2, 0, 0, 0);
    }
    #pragma unroll
    for (int r = 0; r < 4; ++r) {
        int rw = wave * 16 + quad * 4 + r;
        float ds = dis[rw];
        unsigned short* tr = t0 + (size_t)rw * N_CLASS;
        tr[m] = __half_as_ushort(__float2half(ds * acc0[r]));
        tr[16 + m] = __half_as_ushort(__float2half(ds * acc1[r]));
        if (m < 8) tr[32 + m] = __half_as_ushort(__float2half(ds * acc2[r]));
    }
}

// ---------------------------------------------------------------------------
// Group-per-node gather: 12 groups x 5 lanes per wave; lane sl owns bytes
// [16*sl, 16*sl+16) of the 80 B row. f32 accumulation in two banks.
struct F8 { float v0, v1, v2, v3, v4, v5, v6, v7; };

__device__ __forceinline__ void acc8(F8& a, uint4 r) {
    float2 f0 = __half22float2(u2h(r.x));
    float2 f1 = __half22float2(u2h(r.y));
    float2 f2 = __half22float2(u2h(r.z));
    float2 f3 = __half22float2(u2h(r.w));
    a.v0 += f0.x; a.v1 += f0.y; a.v2 += f1.x; a.v3 += f1.y;
    a.v4 += f2.x; a.v5 += f2.y; a.v6 += f3.x; a.v7 += f3.y;
}

// Shared gather over edge range [eBp[d], eEp[d]). SELFH=1: add self row when
// d in half0 (pass 0); SELFH=0: when d in half1 (pass 1) -- keeps every
// table access inside the pass's L2-resident half. srcsB holds byte offsets.
// Main loop: 8 gathers in flight (MLP-bound fix, round 12); A/B alternation
// matches two consecutive 4-wide iterations -> identical summation order.
// Ghost lanes 60-63 shadow group 11 (results discarded via act).
#define GATHERG(tin, eBp, eEp, SELFH)                                          \
    int wv = (blockIdx.x * blockDim.x + threadIdx.x) >> 6;                     \
    int lane = threadIdx.x & 63;                                               \
    int g = lane / 5;                                                          \
    int sl = lane - g * 5;                                                     \
    if (g > 11) { g = 11; sl = 0; }                                            \
    int d = wv * 12 + g;                                                       \
    int act = (lane < 60) && (d < N);                                          \
    int dc = min(d, N - 1);                                                    \
    int e0 = (eBp)[dc];                                                        \
    int e1 = (eEp)[dc];                                                        \
    if (d >= N) e1 = e0;                                                       \
    int slo = sl << 4;                                                         \
    const char* tbs = (const char*)(tin) + slo;                                \
    F8 A = {0,0,0,0,0,0,0,0}, B = {0,0,0,0,0,0,0,0};                           \
    if ((SELFH) ? (dc < HALF_SPLIT) : (dc >= HALF_SPLIT)) {                    \
        uint4 rs = *reinterpret_cast<const uint4*>(tbs + (size_t)dc * 80);     \
        acc8(A, rs);                            /* self term row d */          \
    }                                                                          \
    int e = e0;                                                                \
    int ea = min(e1, (e0 + 3) & ~3);                                           \
    for (; e < ea; ++e) {                       /* align to 16 B */            \
        unsigned o = (unsigned)srcsB[e];                                       \
        uint4 r = *reinterpret_cast<const uint4*>(tbs + o);                    \
        acc8(A, r);                                                            \
    }                                                                          \
    for (; e + 8 <= e1; e += 8) {               /* 8 gathers in flight */      \
        int4 oa = *reinterpret_cast<const int4*>(srcsB + e);                   \
        int4 ob = *reinterpret_cast<const int4*>(srcsB + e + 4);               \
        uint4 r0 = *reinterpret_cast<const uint4*>(tbs + (unsigned)oa.x);      \
        uint4 r1 = *reinterpret_cast<const uint4*>(tbs + (unsigned)oa.y);      \
        uint4 r2 = *reinterpret_cast<const uint4*>(tbs + (unsigned)oa.z);      \
        uint4 r3 = *reinterpret_cast<const uint4*>(tbs + (unsigned)oa.w);      \
        uint4 r4 = *reinterpret_cast<const uint4*>(tbs + (unsigned)ob.x);      \
        uint4 r5 = *reinterpret_cast<const uint4*>(tbs + (unsigned)ob.y);      \
        uint4 r6 = *reinterpret_cast<const uint4*>(tbs + (unsigned)ob.z);      \
        uint4 r7 = *reinterpret_cast<const uint4*>(tbs + (unsigned)ob.w);      \
        acc8(A, r0); acc8(B, r1); acc8(A, r2); acc8(B, r3);                    \
        acc8(A, r4); acc8(B, r5); acc8(A, r6); acc8(B, r7);                    \
    }                                                                          \
    for (; e + 4 <= e1; e += 4) {               /* 4-wide remainder */         \
        int4 o4 = *reinterpret_cast<const int4*>(srcsB + e);                   \
        uint4 r0 = *reinterpret_cast<const uint4*>(tbs + (unsigned)o4.x);      \
        uint4 r1 = *reinterpret_cast<const uint4*>(tbs + (unsigned)o4.y);      \
        uint4 r2 = *reinterpret_cast<const uint4*>(tbs + (unsigned)o4.z);      \
        uint4 r3 = *reinterpret_cast<const uint4*>(tbs + (unsigned)o4.w);      \
        acc8(A, r0); acc8(B, r1); acc8(A, r2); acc8(B, r3);                    \
    }                                                                          \
    for (; e < e1; ++e) {                       /* tail <= 3 edges */          \
        unsigned o = (unsigned)srcsB[e];                                       \
        uint4 r = *reinterpret_cast<const uint4*>(tbs + o);                    \
        acc8(A, r);                                                            \
    }                                                                          \
    A.v0 += B.v0; A.v1 += B.v1; A.v2 += B.v2; A.v3 += B.v3;                    \
    A.v4 += B.v4; A.v5 += B.v5; A.v6 += B.v6; A.v7 += B.v7;

// Middle hop, pass 0 (src < HALF): tout[d] = raw f16 partial sums.
__global__ __launch_bounds__(256) void prop_hop0(
    const unsigned short* __restrict__ tin, unsigned short* __restrict__ tout,
    const int* __restrict__ starts, const int* __restrict__ mid,
    const int* __restrict__ srcsB, int N)
{
    GATHERG(tin, starts, mid, 1)
    if (act) {
        uint4 o;
        o.x = h2u(__floats2half2_rn(A.v0, A.v1));
        o.y = h2u(__floats2half2_rn(A.v2, A.v3));
        o.z = h2u(__floats2half2_rn(A.v4, A.v5));
        o.w = h2u(__floats2half2_rn(A.v6, A.v7));
        *reinterpret_cast<uint4*>((char*)tout + (size_t)d * 80 + slo) = o;
    }
}

// Middle hop, pass 1 (src >= HALF): tout[d] = f16( dd^2 * (partial + sum) ).
__global__ __launch_bounds__(256) void prop_hop1(
    const unsigned short* __restrict__ tin, unsigned short* __restrict__ tout,
    const int* __restrict__ starts, const int* __restrict__ mid,
    const int* __restrict__ srcsB, const float* __restrict__ dis, int N)
{
    GATHERG(tin, mid, starts + 1, 0)
    if (act) {
        uint4 pr = *reinterpret_cast<const uint4*>((const char*)tout + (size_t)d * 80 + slo);
        acc8(A, pr);
        float dd = dis[dc];
        float sc = dd * dd;
        uint4 o;
        o.x = h2u(__floats2half2_rn(sc * A.v0, sc * A.v1));
        o.y = h2u(__floats2half2_rn(sc * A.v2, sc * A.v3));
        o.z = h2u(__floats2half2_rn(sc * A.v4, sc * A.v5));
        o.w = h2u(__floats2half2_rn(sc * A.v6, sc * A.v7));
        *reinterpret_cast<uint4*>((char*)tout + (size_t)d * 80 + slo) = o;
    }
}

// Final hop, pass 0: out[d][*] = raw f32 partial (t[d] + sum over half0).
__global__ __launch_bounds__(256) void prop_fin0(
    const unsigned short* __restrict__ tin, float* __restrict__ out,
    const int* __restrict__ starts, const int* __restrict__ mid,
    const int* __restrict__ srcsB, int N)
{
    GATHERG(tin, starts, mid, 1)
    if (act) {
        float* ro = out + (size_t)d * N_CLASS + sl * 8;
        *reinterpret_cast<float4*>(ro)     = make_float4(A.v0, A.v1, A.v2, A.v3);
        *reinterpret_cast<float4*>(ro + 4) = make_float4(A.v4, A.v5, A.v6, A.v7);
    }
}

// Final hop, pass 1: sum over half1 + partial, bias + log_softmax.
// Softmax reduce = 4 rotate-shfls within the 5-lane group (12 nodes/wave).
// Final stores are nontemporal (out is never re-read).
__global__ __launch_bounds__(256) void prop_fin1(
    const unsigned short* __restrict__ tin, float* __restrict__ out,
    const int* __restrict__ starts, const int* __restrict__ mid,
    const int* __restrict__ srcsB, const float* __restrict__ dis,
    const float* __restrict__ bias, int N)
{
    GATHERG(tin, mid, starts + 1, 0)
    float dd = dis[dc];
    const float* pp = out + (size_t)dc * N_CLASS + sl * 8;
    float4 plo = *reinterpret_cast<const float4*>(pp);
    float4 phi = *reinterpret_cast<const float4*>(pp + 4);
    float4 blo = reinterpret_cast<const float4*>(bias)[sl * 2];       // sl<5
    float4 bhi = reinterpret_cast<const float4*>(bias)[sl * 2 + 1];
    float v0 = dd * (plo.x + A.v0) + blo.x, v1 = dd * (plo.y + A.v1) + blo.y;
    float v2 = dd * (plo.z + A.v2) + blo.z, v3 = dd * (plo.w + A.v3) + blo.w;
    float v4 = dd * (phi.x + A.v4) + bhi.x, v5 = dd * (phi.y + A.v5) + bhi.y;
    float v6 = dd * (phi.z + A.v6) + bhi.z, v7 = dd * (phi.w + A.v7) + bhi.w;
    float mx = fmaxf(fmaxf(fmaxf(v0, v1), fmaxf(v2, v3)),
                     fmaxf(fmaxf(v4, v5), fmaxf(v6, v7)));
    int rot = g * 5 + ((sl + 1 == 5) ? 0 : sl + 1);     // next lane in group
    float tmx = mx;
    #pragma unroll
    for (int k = 0; k < 4; ++k) { tmx = __shfl(tmx, rot); mx = fmaxf(mx, tmx); }
    float s = expf(v0 - mx) + expf(v1 - mx) + expf(v2 - mx) + expf(v3 - mx)
            + expf(v4 - mx) + expf(v5 - mx) + expf(v6 - mx) + expf(v7 - mx);
    float ts = s;
    #pragma unroll
    for (int k = 0; k < 4; ++k) { ts = __shfl(ts, rot); s += ts; }
    if (act) {
        float ls = mx + logf(s);
        float* ro = out + (size_t)d * N_CLASS + sl * 8;
        floatx4 lo = {v0 - ls, v1 - ls, v2 - ls, v3 - ls};
        floatx4 hi = {v4 - ls, v5 - ls, v6 - ls, v7 - ls};
        __builtin_nontemporal_store(lo, reinterpret_cast<floatx4*>(ro));
        __builtin_nontemporal_store(hi, reinterpret_cast<floatx4*>(ro) + 1);
    }
}

// ---------------------------------------------------------------------------
extern "C" void kernel_launch(void* const* d_in, const int* in_sizes, int n_in,
                              void* d_out, int out_size, void* d_ws, size_t ws_size,
                              hipStream_t stream) {
    const float* feature = (const float*)d_in[0];   // [N, 128]
    const float* weight  = (const float*)d_in[1];   // [40, 128]
    const float* bias    = (const float*)d_in[2];   // [40]
    const int*   ei      = (const int*)d_in[3];     // [2, E] (int32 or int64 words)
    const int N = N_NODES;
    const int E = in_sizes[3] / 2;

    size_t off = 0;
    auto take = [&](size_t bytes) { size_t o = off; off += (bytes + 255) & ~(size_t)255; return o; };
    char* ws = (char*)d_ws;
    int*   bCount    = (int*)  (ws + take((size_t)NBALLOC * 4));
    int*   starts    = (int*)  (ws + take((size_t)(N + 1) * 4));
    int*   mid       = (int*)  (ws + take((size_t)N * 4));
    float* dis       = (float*)(ws + take((size_t)N * 4));
    int*   srcsB     = (int*)  (ws + take((size_t)E * 4));
    // t0+t1 (16 MB contiguous) also host tmp (per-bucket record regions,
    // NBUSED*CAP*4 = 13.6 MB; tmp dead once p4 finishes, before transform)
    unsigned short* t0 = (unsigned short*)(ws + take((size_t)N * N_CLASS * 2));
    unsigned short* t1 = (unsigned short*)(ws + take((size_t)N * N_CLASS * 2));
    unsigned int* tmp = (unsigned int*)t0;

    // --- build CSR (single-level fine bucketed counting sort) ---
    hipMemsetAsync(bCount, 0, (size_t)NBALLOC * 4, stream);
    const int p3grid = (E + P3BLK - 1) / P3BLK;
    p3a_scatter<<<p3grid, 256, 0, stream>>>(ei, E, bCount, tmp);
    p4_sort<<<NBUSED, 256, 0, stream>>>(tmp, bCount, starts, mid, dis, srcsB, N, E);

    // --- transform (MFMA, pre-scaled f16 rows) then 2 hops x 2 src-passes ---
    const int ntile = (N + 15) / 16;
    const int tblocks = (ntile * 64 + 255) / 256;
    transform_mfma<<<tblocks, 256, 0, stream>>>(feature, weight, dis, t0, N);
    const int nwaves = (N + 11) / 12;                     // 12 nodes per wave
    const int nodeBlocks = (nwaves * 64 + 255) / 256;
    prop_hop0<<<nodeBlocks, 256, 0, stream>>>(t0, t1, starts, mid, srcsB, N);
    prop_hop1<<<nodeBlocks, 256, 0, stream>>>(t0, t1, starts, mid, srcsB, dis, N);
    prop_fin0<<<nodeBlocks, 256, 0, stream>>>(t1, (float*)d_out, starts, mid, srcsB, N);
    prop_fin1<<<nodeBlocks, 256, 0, stream>>>(t1, (float*)d_out, starts, mid, srcsB,
                                              dis, bias, N);
}

// Round 13
// 283.275 us; speedup vs baseline: 1.1712x; 1.0641x over previous
//
#include <hip/hip_runtime.h>
#include <hip/hip_bf16.h>
#include <hip/hip_fp16.h>
#include <math.h>

// SGC: out = log_softmax( S^2 X W^T + b ), S = D^-1/2 (A+I) D^-1/2
// t0 = dis .* (X W^T) in *f16* (pre-scaled 80 B rows).
// Props (round 13): the two src-range passes of each hop are MERGED into one
// kernel. Pass 1 of a node depends only on that node's own pass-0 partial
// (same wave/group), so no kernel boundary is needed for correctness; the
// half0-then-half1 gather ORDER inside each wave preserves the machine-wide
// L2 phase separation (half = 4 MB, L2-resident). This deletes the partial
// round-trips (hop: 16 MB f16, fin: 32 MB f32) and 2 launches outright.
// Gather: 5-lane group per dst, 12 nodes/wave, f32 accum, 8 edges in flight.
// r10 lesson kept: NO nontemporal on re-read data; only fin final store NT.
// CSR build: r7 block-local LDS counting sort (P3BLK=6250; probes r8/r9
// null) with r11 folds (is64 in p3a, p2 scan in p4). 6 dispatches total.

#define N_NODES 100000
#define N_FEAT  128
#define N_CLASS 40

#define RANGE   256           // dsts per fine bucket (pow2: dst>>8)
#define NBALLOC 512
#define NBUSED  391           // ceil(100000/256)
#define CAP     8704          // fine bucket cap (mean 8192 + ~5.7 sigma)
#define P3BLK   6250          // edges per p3a block (grid = ceil(E/P3BLK))
#define HALF_SPLIT 50000      // src-range split point (table half = 4 MB)

typedef __attribute__((ext_vector_type(8))) short short8;   // 8 bf16 (4 VGPRs)
typedef __attribute__((ext_vector_type(4))) float floatx4;  // f32x4 (NT-able)

__device__ __forceinline__ int edge_word(const int* ei, int elem, int is64) {
    return is64 ? ei[2 * elem] : ei[elem];
}

// P3a: per-block is64 detect (ballot over first 64 odd words), then
// block-local LDS counting sort over 512 fine buckets, then coalesced
// bucket-grouped run writes into fixed-stride regions tmp[f*CAP + p].
// bucketCount (pre-zeroed by memset) accumulates global per-bucket totals.
__global__ __launch_bounds__(256) void p3a_scatter(
    const int* __restrict__ ei, int E,
    int* __restrict__ bucketCount, unsigned int* __restrict__ tmp)
{
    __shared__ unsigned int srt[P3BLK];     // bucket-grouped records
    __shared__ unsigned short fb[P3BLK];    // bucket id per record
    __shared__ int hist[NBALLOC];
    __shared__ int lbase[NBALLOC];          // block-local exclusive scan
    __shared__ int gbase[NBALLOC];          // global run base per bucket
    __shared__ int cur[NBALLOC];
    __shared__ int sc[256];
    __shared__ int s_is64;
    int t = threadIdx.x;
    for (int i = t; i < NBALLOC; i += 256) hist[i] = 0;
    if (t < 64) {                            // wave 0: int32/int64 detect
        int nz = (ei[2 * t + 1] != 0) ? 1 : 0;
        unsigned long long bl = __ballot(nz);
        if (t == 0) s_is64 = (bl == 0ull) ? 1 : 0;
    }
    __syncthreads();
    int is64 = s_is64;
    int per = (E + gridDim.x - 1) / gridDim.x;
    int e0 = blockIdx.x * per;
    int e1 = min(E, e0 + per);
    int n = e1 - e0;
    for (int e = e0 + t; e < e1; e += 256) {
        int c = edge_word(ei, E + e, is64);
        atomicAdd(&hist[c >> 8], 1);
    }
    __syncthreads();
    int h0 = hist[2 * t], h1 = hist[2 * t + 1];
    sc[t] = h0 + h1;
    __syncthreads();
    for (int o = 1; o < 256; o <<= 1) {
        int y = (t >= o) ? sc[t - o] : 0;
        __syncthreads();
        sc[t] += y;
        __syncthreads();
    }
    int excl = sc[t] - (h0 + h1);
    lbase[2 * t] = excl;
    lbase[2 * t + 1] = excl + h0;
    cur[2 * t] = excl;
    cur[2 * t + 1] = excl + h0;
    gbase[2 * t]     = h0 ? atomicAdd(&bucketCount[2 * t], h0) : 0;
    gbase[2 * t + 1] = h1 ? atomicAdd(&bucketCount[2 * t + 1], h1) : 0;
    __syncthreads();
    for (int e = e0 + t; e < e1; e += 256) {
        int c = edge_word(ei, E + e, is64);
        int r = edge_word(ei, e, is64);
        int f = c >> 8;
        int p = atomicAdd(&cur[f], 1);
        srt[p] = ((unsigned)(c & 255) << 24) | (unsigned)r;
        fb[p] = (unsigned short)f;
    }
    __syncthreads();
    for (int i = t; i < n; i += 256) {
        int f = fb[i];
        int p = gbase[f] + (i - lbase[f]);
        if (p < CAP) tmp[(size_t)f * CAP + p] = srt[i];
    }
}

// P4: global scan of bucketCount in-block (p2 folded in) -> base; then
// per-fine-bucket LDS counting sort with 512 keys (dlf*2 + srcHalf) ->
// starts, mid (end of half0 / begin of half1), dis, srcsB (byte offsets,
// src*80, coalesced). Records come from tmp[b*CAP + i] (region-stride).
__global__ __launch_bounds__(256) void p4_sort(
    const unsigned int* __restrict__ tmp, const int* __restrict__ bucketCount,
    int* __restrict__ starts, int* __restrict__ mid, float* __restrict__ dis,
    int* __restrict__ srcsB, int N, int E)
{
    __shared__ int srt[CAP];
    __shared__ int hist[512];
    __shared__ int sc[256];
    __shared__ int cur[512];
    __shared__ int cnt[NBALLOC];
    __shared__ int base_s;
    int b = blockIdx.x, t = threadIdx.x;
    int g0 = b * RANGE;
    int gcnt = N - g0;
    if (gcnt > RANGE) gcnt = RANGE;
    // --- folded p2: scan the 512 global bucket counts for this block's base
    for (int i = t; i < NBALLOC; i += 256) cnt[i] = bucketCount[i];
    __syncthreads();
    int p0 = cnt[2 * t], p1 = cnt[2 * t + 1];
    sc[t] = p0 + p1;
    __syncthreads();
    for (int o = 1; o < 256; o <<= 1) {
        int y = (t >= o) ? sc[t - o] : 0;
        __syncthreads();
        sc[t] += y;
        __syncthreads();
    }
    if (t == 0) {
        int pairs = b >> 1;
        int base = (pairs > 0) ? sc[pairs - 1] : 0;
        if (b & 1) base += cnt[b - 1];
        base_s = base;
        if (b == 0) starts[N_NODES] = E;
    }
    __syncthreads();
    int base = base_s;
    int n = cnt[b];
    int nr = min(n, CAP);                       // records actually present
    const unsigned int* rec = tmp + (size_t)b * CAP;
    hist[t] = 0;
    hist[t + 256] = 0;
    __syncthreads();
    for (int i = t; i < nr; i += 256) {
        unsigned v = rec[i];
        int key = (int)((v >> 24) << 1) | (((v & 0xFFFFFFu) >= HALF_SPLIT) ? 1 : 0);
        atomicAdd(&hist[key], 1);
    }
    __syncthreads();
    int c0 = hist[2 * t], c1 = hist[2 * t + 1];
    sc[t] = c0 + c1;
    __syncthreads();
    for (int o = 1; o < 256; o <<= 1) {
        int y = (t >= o) ? sc[t - o] : 0;
        __syncthreads();
        sc[t] += y;
        __syncthreads();
    }
    int excl = sc[t] - (c0 + c1);
    if (t < gcnt) {
        starts[g0 + t] = base + excl;
        mid[g0 + t] = base + excl + c0;
        dis[g0 + t] = rsqrtf((float)(c0 + c1 + 1));   // +1 self-loop
    }
    cur[2 * t] = excl;
    cur[2 * t + 1] = excl + c0;
    __syncthreads();
    for (int i = t; i < nr; i += 256) {
        unsigned v = rec[i];
        int src = (int)(v & 0xFFFFFFu);
        int key = (int)((v >> 24) << 1) | ((src >= HALF_SPLIT) ? 1 : 0);
        int p = atomicAdd(&cur[key], 1);
        srt[p] = src * 80;                       // pre-scaled byte offset
    }
    __syncthreads();
    for (int i = t; i < nr; i += 256) srcsB[base + i] = srt[i];
}

// ---------------------------------------------------------------------------
__device__ __forceinline__ unsigned short f2bf(float f) {   // RTN f32 -> bf16
    unsigned u = __float_as_uint(f);
    unsigned r = u + 0x7FFFu + ((u >> 16) & 1u);
    return (unsigned short)(r >> 16);
}
__device__ __forceinline__ __half2 u2h(unsigned w) {
    union { unsigned u; __half2 h; } c; c.u = w; return c.h;
}
__device__ __forceinline__ unsigned h2u(__half2 h) {
    union { unsigned u; __half2 h; } c; c.h = h; return c.u;
}

// t0 = dis .* (X @ W^T), f16, row stride 40 (80 B). One wave per 16 nodes.
// MFMA on bf16 inputs (f32 accumulate), output stored f16.
__global__ __launch_bounds__(256) void transform_mfma(
    const float* __restrict__ x, const float* __restrict__ W,
    const float* __restrict__ dis, unsigned short* __restrict__ t0, int N)
{
    __shared__ uint4 Wl[3 * 4 * 64];        // B frags, bf16-packed: 12 KiB
    int t = threadIdx.x;
    for (int i = t; i < 3 * 4 * 64; i += 256) {
        int lane = i & 63;
        int kc = (i >> 6) & 3;
        int nt = i >> 8;
        int n = nt * 16 + (lane & 15);
        int k = kc * 32 + (lane >> 4) * 8;
        union { unsigned short s[8]; uint4 v; } u;
        #pragma unroll
        for (int j = 0; j < 8; ++j)
            u.s[j] = (n < N_CLASS) ? f2bf(W[n * N_FEAT + k + j]) : (unsigned short)0;
        Wl[i] = u.v;
    }
    __syncthreads();
    int wave = (blockIdx.x * blockDim.x + threadIdx.x) >> 6;
    int lane = threadIdx.x & 63;
    int ntile = (N + 15) / 16;
    if (wave >= ntile) return;
    int m = lane & 15, quad = lane >> 4;
    int row = wave * 16 + m;
    const short8* Wf = reinterpret_cast<const short8*>(Wl);
    floatx4 acc0 = {0.f, 0.f, 0.f, 0.f}, acc1 = acc0, acc2 = acc0;
    #pragma unroll
    for (int kc = 0; kc < 4; ++kc) {
        const float4* xr = reinterpret_cast<const float4*>(
            x + (size_t)row * N_FEAT + kc * 32 + quad * 8);
        float4 a0 = xr[0], a1 = xr[1];
        short8 af;
        af[0] = f2bf(a0.x); af[1] = f2bf(a0.y); af[2] = f2bf(a0.z); af[3] = f2bf(a0.w);
        af[4] = f2bf(a1.x); af[5] = f2bf(a1.y); af[6] = f2bf(a1.z); af[7] = f2bf(a1.w);
        short8 b0 = Wf[(0 * 4 + kc) * 64 + lane];
        short8 b1 = Wf[(1 * 4 + kc) * 64 + lane];
        short8 b2 = Wf[(2 * 4 + kc) * 64 + lane];
        acc0 = __builtin_amdgcn_mfma_f32_16x16x32_bf16(af, b0, acc0, 0, 0, 0);
        acc1 = __builtin_amdgcn_mfma_f32_16x16x32_bf16(af, b1, acc1, 0, 0, 0);
        acc2 = __builtin_amdgcn_mfma_f32_16x16x32_bf16(af, b2, acc2, 0, 0, 0);
    }
    #pragma unroll
    for (int r = 0; r < 4; ++r) {
        int rw = wave * 16 + quad * 4 + r;
        float ds = dis[rw];
        unsigned short* tr = t0 + (size_t)rw * N_CLASS;
        tr[m] = __half_as_ushort(__float2half(ds * acc0[r]));
        tr[16 + m] = __half_as_ushort(__float2half(ds * acc1[r]));
        if (m < 8) tr[32 + m] = __half_as_ushort(__float2half(ds * acc2[r]));
    }
}

// ---------------------------------------------------------------------------
// Group-per-node gather: 12 groups x 5 lanes per wave; lane sl owns bytes
// [16*sl, 16*sl+16) of the 80 B row. f32 accumulation in two banks.
struct F8 { float v0, v1, v2, v3, v4, v5, v6, v7; };

__device__ __forceinline__ void acc8(F8& a, uint4 r) {
    float2 f0 = __half22float2(u2h(r.x));
    float2 f1 = __half22float2(u2h(r.y));
    float2 f2 = __half22float2(u2h(r.z));
    float2 f3 = __half22float2(u2h(r.w));
    a.v0 += f0.x; a.v1 += f0.y; a.v2 += f1.x; a.v3 += f1.y;
    a.v4 += f2.x; a.v5 += f2.y; a.v6 += f3.x; a.v7 += f3.y;
}

// Gather one edge range [e0, e1): 8 edges in flight, A/B bank alternation.
__device__ __forceinline__ void gather_range(
    const char* tbs, const int* __restrict__ srcsB, int e0, int e1,
    F8& A, F8& B)
{
    int e = e0;
    int ea = min(e1, (e0 + 3) & ~3);
    for (; e < ea; ++e) {                       // align to 16 B
        unsigned o = (unsigned)srcsB[e];
        uint4 r = *reinterpret_cast<const uint4*>(tbs + o);
        acc8(A, r);
    }
    for (; e + 8 <= e1; e += 8) {               // 8 gathers in flight
        int4 oa = *reinterpret_cast<const int4*>(srcsB + e);
        int4 ob = *reinterpret_cast<const int4*>(srcsB + e + 4);
        uint4 r0 = *reinterpret_cast<const uint4*>(tbs + (unsigned)oa.x);
        uint4 r1 = *reinterpret_cast<const uint4*>(tbs + (unsigned)oa.y);
        uint4 r2 = *reinterpret_cast<const uint4*>(tbs + (unsigned)oa.z);
        uint4 r3 = *reinterpret_cast<const uint4*>(tbs + (unsigned)oa.w);
        uint4 r4 = *reinterpret_cast<const uint4*>(tbs + (unsigned)ob.x);
        uint4 r5 = *reinterpret_cast<const uint4*>(tbs + (unsigned)ob.y);
        uint4 r6 = *reinterpret_cast<const uint4*>(tbs + (unsigned)ob.z);
        uint4 r7 = *reinterpret_cast<const uint4*>(tbs + (unsigned)ob.w);
        acc8(A, r0); acc8(B, r1); acc8(A, r2); acc8(B, r3);
        acc8(A, r4); acc8(B, r5); acc8(A, r6); acc8(B, r7);
    }
    for (; e + 4 <= e1; e += 4) {               // 4-wide remainder
        int4 o4 = *reinterpret_cast<const int4*>(srcsB + e);
        uint4 r0 = *reinterpret_cast<const uint4*>(tbs + (unsigned)o4.x);
        uint4 r1 = *reinterpret_cast<const uint4*>(tbs + (unsigned)o4.y);
        uint4 r2 = *reinterpret_cast<const uint4*>(tbs + (unsigned)o4.z);
        uint4 r3 = *reinterpret_cast<const uint4*>(tbs + (unsigned)o4.w);
        acc8(A, r0); acc8(B, r1); acc8(A, r2); acc8(B, r3);
    }
    for (; e < e1; ++e) {                       // tail <= 3 edges
        unsigned o = (unsigned)srcsB[e];
        uint4 r = *reinterpret_cast<const uint4*>(tbs + o);
        acc8(A, r);
    }
}

// Shared prologue + merged two-half gather. Self term is added in the half
// containing d (keeps every table access inside the currently-hot half).
#define GATHER_BOTH(tin)                                                       \
    int wv = (blockIdx.x * blockDim.x + threadIdx.x) >> 6;                     \
    int lane = threadIdx.x & 63;                                               \
    int g = lane / 5;                                                          \
    int sl = lane - g * 5;                                                     \
    if (g > 11) { g = 11; sl = 0; }                                            \
    int d = wv * 12 + g;                                                       \
    int act = (lane < 60) && (d < N);                                          \
    int dc = min(d, N - 1);                                                    \
    int e0 = starts[dc];                                                       \
    int m  = mid[dc];                                                          \
    int e1 = starts[dc + 1];                                                   \
    if (d >= N) { m = e0; e1 = e0; }                                           \
    int slo = sl << 4;                                                         \
    const char* tbs = (const char*)(tin) + slo;                                \
    F8 A = {0,0,0,0,0,0,0,0}, B = {0,0,0,0,0,0,0,0};                           \
    if (dc < HALF_SPLIT) {                      /* self in half0 phase */      \
        uint4 rs = *reinterpret_cast<const uint4*>(tbs + (size_t)dc * 80);     \
        acc8(A, rs);                                                           \
    }                                                                          \
    gather_range(tbs, srcsB, e0, m, A, B);      /* half0 edges */              \
    if (dc >= HALF_SPLIT) {                     /* self in half1 phase */      \
        uint4 rs = *reinterpret_cast<const uint4*>(tbs + (size_t)dc * 80);     \
        acc8(A, rs);                                                           \
    }                                                                          \
    gather_range(tbs, srcsB, m, e1, A, B);      /* half1 edges */              \
    A.v0 += B.v0; A.v1 += B.v1; A.v2 += B.v2; A.v3 += B.v3;                    \
    A.v4 += B.v4; A.v5 += B.v5; A.v6 += B.v6; A.v7 += B.v7;

// Middle hop (merged halves): tout[d] = f16( dd^2 * (t[d] + sum t[src]) ).
__global__ __launch_bounds__(256) void prop_hop(
    const unsigned short* __restrict__ tin, unsigned short* __restrict__ tout,
    const int* __restrict__ starts, const int* __restrict__ mid,
    const int* __restrict__ srcsB, const float* __restrict__ dis, int N)
{
    GATHER_BOTH(tin)
    if (act) {
        float dd = dis[dc];
        float sc = dd * dd;
        uint4 o;
        o.x = h2u(__floats2half2_rn(sc * A.v0, sc * A.v1));
        o.y = h2u(__floats2half2_rn(sc * A.v2, sc * A.v3));
        o.z = h2u(__floats2half2_rn(sc * A.v4, sc * A.v5));
        o.w = h2u(__floats2half2_rn(sc * A.v6, sc * A.v7));
        *reinterpret_cast<uint4*>((char*)tout + (size_t)d * 80 + slo) = o;
    }
}

// Final hop (merged halves) fused with bias + log_softmax. Softmax reduce =
// 4 rotate-shfls within the 5-lane group. Final stores NT (never re-read).
__global__ __launch_bounds__(256) void prop_fin(
    const unsigned short* __restrict__ tin, float* __restrict__ out,
    const int* __restrict__ starts, const int* __restrict__ mid,
    const int* __restrict__ srcsB, const float* __restrict__ dis,
    const float* __restrict__ bias, int N)
{
    GATHER_BOTH(tin)
    float dd = dis[dc];
    float4 blo = reinterpret_cast<const float4*>(bias)[sl * 2];       // sl<5
    float4 bhi = reinterpret_cast<const float4*>(bias)[sl * 2 + 1];
    float v0 = dd * A.v0 + blo.x, v1 = dd * A.v1 + blo.y;
    float v2 = dd * A.v2 + blo.z, v3 = dd * A.v3 + blo.w;
    float v4 = dd * A.v4 + bhi.x, v5 = dd * A.v5 + bhi.y;
    float v6 = dd * A.v6 + bhi.z, v7 = dd * A.v7 + bhi.w;
    float mx = fmaxf(fmaxf(fmaxf(v0, v1), fmaxf(v2, v3)),
                     fmaxf(fmaxf(v4, v5), fmaxf(v6, v7)));
    int rot = g * 5 + ((sl + 1 == 5) ? 0 : sl + 1);     // next lane in group
    float tmx = mx;
    #pragma unroll
    for (int k = 0; k < 4; ++k) { tmx = __shfl(tmx, rot); mx = fmaxf(mx, tmx); }
    float s = expf(v0 - mx) + expf(v1 - mx) + expf(v2 - mx) + expf(v3 - mx)
            + expf(v4 - mx) + expf(v5 - mx) + expf(v6 - mx) + expf(v7 - mx);
    float ts = s;
    #pragma unroll
    for (int k = 0; k < 4; ++k) { ts = __shfl(ts, rot); s += ts; }
    if (act) {
        float ls = mx + logf(s);
        float* ro = out + (size_t)d * N_CLASS + sl * 8;
        floatx4 lo = {v0 - ls, v1 - ls, v2 - ls, v3 - ls};
        floatx4 hi = {v4 - ls, v5 - ls, v6 - ls, v7 - ls};
        __builtin_nontemporal_store(lo, reinterpret_cast<floatx4*>(ro));
        __builtin_nontemporal_store(hi, reinterpret_cast<floatx4*>(ro) + 1);
    }
}

// ---------------------------------------------------------------------------
extern "C" void kernel_launch(void* const* d_in, const int* in_sizes, int n_in,
                              void* d_out, int out_size, void* d_ws, size_t ws_size,
                              hipStream_t stream) {
    const float* feature = (const float*)d_in[0];   // [N, 128]
    const float* weight  = (const float*)d_in[1];   // [40, 128]
    const float* bias    = (const float*)d_in[2];   // [40]
    const int*   ei      = (const int*)d_in[3];     // [2, E] (int32 or int64 words)
    const int N = N_NODES;
    const int E = in_sizes[3] / 2;

    size_t off = 0;
    auto take = [&](size_t bytes) { size_t o = off; off += (bytes + 255) & ~(size_t)255; return o; };
    char* ws = (char*)d_ws;
    int*   bCount    = (int*)  (ws + take((size_t)NBALLOC * 4));
    int*   starts    = (int*)  (ws + take((size_t)(N + 1) * 4));
    int*   mid       = (int*)  (ws + take((size_t)N * 4));
    float* dis       = (float*)(ws + take((size_t)N * 4));
    int*   srcsB     = (int*)  (ws + take((size_t)E * 4));
    // t0+t1 (16 MB contiguous) also host tmp (per-bucket record regions,
    // NBUSED*CAP*4 = 13.6 MB; tmp dead once p4 finishes, before transform)
    unsigned short* t0 = (unsigned short*)(ws + take((size_t)N * N_CLASS * 2));
    unsigned short* t1 = (unsigned short*)(ws + take((size_t)N * N_CLASS * 2));
    unsigned int* tmp = (unsigned int*)t0;

    // --- build CSR (single-level fine bucketed counting sort) ---
    hipMemsetAsync(bCount, 0, (size_t)NBALLOC * 4, stream);
    const int p3grid = (E + P3BLK - 1) / P3BLK;
    p3a_scatter<<<p3grid, 256, 0, stream>>>(ei, E, bCount, tmp);
    p4_sort<<<NBUSED, 256, 0, stream>>>(tmp, bCount, starts, mid, dis, srcsB, N, E);

    // --- transform (MFMA, pre-scaled f16 rows) then 2 merged-half hops ---
    const int ntile = (N + 15) / 16;
    const int tblocks = (ntile * 64 + 255) / 256;
    transform_mfma<<<tblocks, 256, 0, stream>>>(feature, weight, dis, t0, N);
    const int nwaves = (N + 11) / 12;                     // 12 nodes per wave
    const int nodeBlocks = (nwaves * 64 + 255) / 256;
    prop_hop<<<nodeBlocks, 256, 0, stream>>>(t0, t1, starts, mid, srcsB, dis, N);
    prop_fin<<<nodeBlocks, 256, 0, stream>>>(t1, (float*)d_out, starts, mid, srcsB,
                                             dis, bias, N);
}

// Round 14
// 266.993 us; speedup vs baseline: 1.2426x; 1.0610x over previous
//
#include <hip/hip_runtime.h>
#include <hip/hip_bf16.h>
#include <hip/hip_fp16.h>
#include <math.h>

// SGC: out = log_softmax( S^2 X W^T + b ), S = D^-1/2 (A+I) D^-1/2
// t0 = dis .* (X W^T) in *f16* (pre-scaled 80 B rows).
// Props (r13, proven): merged two-half hops (half0-then-half1 gather order
// per wave keeps each 4 MB table half L2-resident; partial round-trips and
// 2 launches deleted). Gather: 5-lane group per dst, 12 nodes/wave, f32
// accum, 8 edges in flight. Only fin's final store is nontemporal.
// CSR build (round 14): p3a widened to 512 THREADS per block with P3BLK
// and grid UNCHANGED -- r8's occupancy probe was confounded (it halved the
// chunk, hurting write-run length). This isolates latency-hiding: same
// byte traffic, same run lengths, 2-3x waves/CU. Scan = 1 bucket/thread.
// p4: r11 folds kept (is64 in p3a, p2 scan in p4). 6 dispatches total.

#define N_NODES 100000
#define N_FEAT  128
#define N_CLASS 40

#define RANGE   256           // dsts per fine bucket (pow2: dst>>8)
#define NBALLOC 512
#define NBUSED  391           // ceil(100000/256)
#define CAP     8704          // fine bucket cap (mean 8192 + ~5.7 sigma)
#define P3BLK   6250          // edges per p3a block (grid = ceil(E/P3BLK))
#define P3THR   512           // p3a threads per block (r14: 2x latency hiding)
#define HALF_SPLIT 50000      // src-range split point (table half = 4 MB)

typedef __attribute__((ext_vector_type(8))) short short8;   // 8 bf16 (4 VGPRs)
typedef __attribute__((ext_vector_type(4))) float floatx4;  // f32x4 (NT-able)

__device__ __forceinline__ int edge_word(const int* ei, int elem, int is64) {
    return is64 ? ei[2 * elem] : ei[elem];
}

// P3a: per-block is64 detect (ballot over first 64 odd words), then
// block-local LDS counting sort over 512 fine buckets, then coalesced
// bucket-grouped run writes into fixed-stride regions tmp[f*CAP + p].
// bucketCount (pre-zeroed by memset) accumulates global per-bucket totals.
// 512 threads: scan is one-bucket-per-thread (9 butterfly steps).
__global__ __launch_bounds__(P3THR) void p3a_scatter(
    const int* __restrict__ ei, int E,
    int* __restrict__ bucketCount, unsigned int* __restrict__ tmp)
{
    __shared__ unsigned int srt[P3BLK];     // bucket-grouped records
    __shared__ unsigned short fb[P3BLK];    // bucket id per record
    __shared__ int hist[NBALLOC];
    __shared__ int lbase[NBALLOC];          // block-local exclusive scan
    __shared__ int gbase[NBALLOC];          // global run base per bucket
    __shared__ int cur[NBALLOC];
    __shared__ int sc[NBALLOC];
    __shared__ int s_is64;
    int t = threadIdx.x;
    if (t < NBALLOC) hist[t] = 0;
    if (t < 64) {                            // wave 0: int32/int64 detect
        int nz = (ei[2 * t + 1] != 0) ? 1 : 0;
        unsigned long long bl = __ballot(nz);
        if (t == 0) s_is64 = (bl == 0ull) ? 1 : 0;
    }
    __syncthreads();
    int is64 = s_is64;
    int per = (E + gridDim.x - 1) / gridDim.x;
    int e0 = blockIdx.x * per;
    int e1 = min(E, e0 + per);
    int n = e1 - e0;
    for (int e = e0 + t; e < e1; e += P3THR) {
        int c = edge_word(ei, E + e, is64);
        atomicAdd(&hist[c >> 8], 1);
    }
    __syncthreads();
    // one-bucket-per-thread exclusive scan over 512 buckets
    int hv = hist[t];
    sc[t] = hv;
    __syncthreads();
    for (int o = 1; o < NBALLOC; o <<= 1) {
        int y = (t >= o) ? sc[t - o] : 0;
        __syncthreads();
        sc[t] += y;
        __syncthreads();
    }
    int excl = sc[t] - hv;
    lbase[t] = excl;
    cur[t] = excl;
    gbase[t] = hv ? atomicAdd(&bucketCount[t], hv) : 0;
    __syncthreads();
    for (int e = e0 + t; e < e1; e += P3THR) {
        int c = edge_word(ei, E + e, is64);
        int r = edge_word(ei, e, is64);
        int f = c >> 8;
        int p = atomicAdd(&cur[f], 1);
        srt[p] = ((unsigned)(c & 255) << 24) | (unsigned)r;
        fb[p] = (unsigned short)f;
    }
    __syncthreads();
    for (int i = t; i < n; i += P3THR) {
        int f = fb[i];
        int p = gbase[f] + (i - lbase[f]);
        if (p < CAP) tmp[(size_t)f * CAP + p] = srt[i];
    }
}

// P4: global scan of bucketCount in-block (p2 folded in) -> base; then
// per-fine-bucket LDS counting sort with 512 keys (dlf*2 + srcHalf) ->
// starts, mid (end of half0 / begin of half1), dis, srcsB (byte offsets,
// src*80, coalesced). Records come from tmp[b*CAP + i] (region-stride).
__global__ __launch_bounds__(256) void p4_sort(
    const unsigned int* __restrict__ tmp, const int* __restrict__ bucketCount,
    int* __restrict__ starts, int* __restrict__ mid, float* __restrict__ dis,
    int* __restrict__ srcsB, int N, int E)
{
    __shared__ int srt[CAP];
    __shared__ int hist[512];
    __shared__ int sc[256];
    __shared__ int cur[512];
    __shared__ int cnt[NBALLOC];
    __shared__ int base_s;
    int b = blockIdx.x, t = threadIdx.x;
    int g0 = b * RANGE;
    int gcnt = N - g0;
    if (gcnt > RANGE) gcnt = RANGE;
    // --- folded p2: scan the 512 global bucket counts for this block's base
    for (int i = t; i < NBALLOC; i += 256) cnt[i] = bucketCount[i];
    __syncthreads();
    int p0 = cnt[2 * t], p1 = cnt[2 * t + 1];
    sc[t] = p0 + p1;
    __syncthreads();
    for (int o = 1; o < 256; o <<= 1) {
        int y = (t >= o) ? sc[t - o] : 0;
        __syncthreads();
        sc[t] += y;
        __syncthreads();
    }
    if (t == 0) {
        int pairs = b >> 1;
        int base = (pairs > 0) ? sc[pairs - 1] : 0;
        if (b & 1) base += cnt[b - 1];
        base_s = base;
        if (b == 0) starts[N_NODES] = E;
    }
    __syncthreads();
    int base = base_s;
    int n = cnt[b];
    int nr = min(n, CAP);                       // records actually present
    const unsigned int* rec = tmp + (size_t)b * CAP;
    hist[t] = 0;
    hist[t + 256] = 0;
    __syncthreads();
    for (int i = t; i < nr; i += 256) {
        unsigned v = rec[i];
        int key = (int)((v >> 24) << 1) | (((v & 0xFFFFFFu) >= HALF_SPLIT) ? 1 : 0);
        atomicAdd(&hist[key], 1);
    }
    __syncthreads();
    int c0 = hist[2 * t], c1 = hist[2 * t + 1];
    sc[t] = c0 + c1;
    __syncthreads();
    for (int o = 1; o < 256; o <<= 1) {
        int y = (t >= o) ? sc[t - o] : 0;
        __syncthreads();
        sc[t] += y;
        __syncthreads();
    }
    int excl = sc[t] - (c0 + c1);
    if (t < gcnt) {
        starts[g0 + t] = base + excl;
        mid[g0 + t] = base + excl + c0;
        dis[g0 + t] = rsqrtf((float)(c0 + c1 + 1));   // +1 self-loop
    }
    cur[2 * t] = excl;
    cur[2 * t + 1] = excl + c0;
    __syncthreads();
    for (int i = t; i < nr; i += 256) {
        unsigned v = rec[i];
        int src = (int)(v & 0xFFFFFFu);
        int key = (int)((v >> 24) << 1) | ((src >= HALF_SPLIT) ? 1 : 0);
        int p = atomicAdd(&cur[key], 1);
        srt[p] = src * 80;                       // pre-scaled byte offset
    }
    __syncthreads();
    for (int i = t; i < nr; i += 256) srcsB[base + i] = srt[i];
}

// ---------------------------------------------------------------------------
__device__ __forceinline__ unsigned short f2bf(float f) {   // RTN f32 -> bf16
    unsigned u = __float_as_uint(f);
    unsigned r = u + 0x7FFFu + ((u >> 16) & 1u);
    return (unsigned short)(r >> 16);
}
__device__ __forceinline__ __half2 u2h(unsigned w) {
    union { unsigned u; __half2 h; } c; c.u = w; return c.h;
}
__device__ __forceinline__ unsigned h2u(__half2 h) {
    union { unsigned u; __half2 h; } c; c.h = h; return c.u;
}

// t0 = dis .* (X @ W^T), f16, row stride 40 (80 B). One wave per 16 nodes.
// MFMA on bf16 inputs (f32 accumulate), output stored f16.
__global__ __launch_bounds__(256) void transform_mfma(
    const float* __restrict__ x, const float* __restrict__ W,
    const float* __restrict__ dis, unsigned short* __restrict__ t0, int N)
{
    __shared__ uint4 Wl[3 * 4 * 64];        // B frags, bf16-packed: 12 KiB
    int t = threadIdx.x;
    for (int i = t; i < 3 * 4 * 64; i += 256) {
        int lane = i & 63;
        int kc = (i >> 6) & 3;
        int nt = i >> 8;
        int n = nt * 16 + (lane & 15);
        int k = kc * 32 + (lane >> 4) * 8;
        union { unsigned short s[8]; uint4 v; } u;
        #pragma unroll
        for (int j = 0; j < 8; ++j)
            u.s[j] = (n < N_CLASS) ? f2bf(W[n * N_FEAT + k + j]) : (unsigned short)0;
        Wl[i] = u.v;
    }
    __syncthreads();
    int wave = (blockIdx.x * blockDim.x + threadIdx.x) >> 6;
    int lane = threadIdx.x & 63;
    int ntile = (N + 15) / 16;
    if (wave >= ntile) return;
    int m = lane & 15, quad = lane >> 4;
    int row = wave * 16 + m;
    const short8* Wf = reinterpret_cast<const short8*>(Wl);
    floatx4 acc0 = {0.f, 0.f, 0.f, 0.f}, acc1 = acc0, acc2 = acc0;
    #pragma unroll
    for (int kc = 0; kc < 4; ++kc) {
        const float4* xr = reinterpret_cast<const float4*>(
            x + (size_t)row * N_FEAT + kc * 32 + quad * 8);
        float4 a0 = xr[0], a1 = xr[1];
        short8 af;
        af[0] = f2bf(a0.x); af[1] = f2bf(a0.y); af[2] = f2bf(a0.z); af[3] = f2bf(a0.w);
        af[4] = f2bf(a1.x); af[5] = f2bf(a1.y); af[6] = f2bf(a1.z); af[7] = f2bf(a1.w);
        short8 b0 = Wf[(0 * 4 + kc) * 64 + lane];
        short8 b1 = Wf[(1 * 4 + kc) * 64 + lane];
        short8 b2 = Wf[(2 * 4 + kc) * 64 + lane];
        acc0 = __builtin_amdgcn_mfma_f32_16x16x32_bf16(af, b0, acc0, 0, 0, 0);
        acc1 = __builtin_amdgcn_mfma_f32_16x16x32_bf16(af, b1, acc1, 0, 0, 0);
        acc2 = __builtin_amdgcn_mfma_f32_16x16x32_bf16(af, b2, acc2, 0, 0, 0);
    }
    #pragma unroll
    for (int r = 0; r < 4; ++r) {
        int rw = wave * 16 + quad * 4 + r;
        float ds = dis[rw];
        unsigned short* tr = t0 + (size_t)rw * N_CLASS;
        tr[m] = __half_as_ushort(__float2half(ds * acc0[r]));
        tr[16 + m] = __half_as_ushort(__float2half(ds * acc1[r]));
        if (m < 8) tr[32 + m] = __half_as_ushort(__float2half(ds * acc2[r]));
    }
}

// ---------------------------------------------------------------------------
// Group-per-node gather: 12 groups x 5 lanes per wave; lane sl owns bytes
// [16*sl, 16*sl+16) of the 80 B row. f32 accumulation in two banks.
struct F8 { float v0, v1, v2, v3, v4, v5, v6, v7; };

__device__ __forceinline__ void acc8(F8& a, uint4 r) {
    float2 f0 = __half22float2(u2h(r.x));
    float2 f1 = __half22float2(u2h(r.y));
    float2 f2 = __half22float2(u2h(r.z));
    float2 f3 = __half22float2(u2h(r.w));
    a.v0 += f0.x; a.v1 += f0.y; a.v2 += f1.x; a.v3 += f1.y;
    a.v4 += f2.x; a.v5 += f2.y; a.v6 += f3.x; a.v7 += f3.y;
}

// Gather one edge range [e0, e1): 8 edges in flight, A/B bank alternation.
__device__ __forceinline__ void gather_range(
    const char* tbs, const int* __restrict__ srcsB, int e0, int e1,
    F8& A, F8& B)
{
    int e = e0;
    int ea = min(e1, (e0 + 3) & ~3);
    for (; e < ea; ++e) {                       // align to 16 B
        unsigned o = (unsigned)srcsB[e];
        uint4 r = *reinterpret_cast<const uint4*>(tbs + o);
        acc8(A, r);
    }
    for (; e + 8 <= e1; e += 8) {               // 8 gathers in flight
        int4 oa = *reinterpret_cast<const int4*>(srcsB + e);
        int4 ob = *reinterpret_cast<const int4*>(srcsB + e + 4);
        uint4 r0 = *reinterpret_cast<const uint4*>(tbs + (unsigned)oa.x);
        uint4 r1 = *reinterpret_cast<const uint4*>(tbs + (unsigned)oa.y);
        uint4 r2 = *reinterpret_cast<const uint4*>(tbs + (unsigned)oa.z);
        uint4 r3 = *reinterpret_cast<const uint4*>(tbs + (unsigned)oa.w);
        uint4 r4 = *reinterpret_cast<const uint4*>(tbs + (unsigned)ob.x);
        uint4 r5 = *reinterpret_cast<const uint4*>(tbs + (unsigned)ob.y);
        uint4 r6 = *reinterpret_cast<const uint4*>(tbs + (unsigned)ob.z);
        uint4 r7 = *reinterpret_cast<const uint4*>(tbs + (unsigned)ob.w);
        acc8(A, r0); acc8(B, r1); acc8(A, r2); acc8(B, r3);
        acc8(A, r4); acc8(B, r5); acc8(A, r6); acc8(B, r7);
    }
    for (; e + 4 <= e1; e += 4) {               // 4-wide remainder
        int4 o4 = *reinterpret_cast<const int4*>(srcsB + e);
        uint4 r0 = *reinterpret_cast<const uint4*>(tbs + (unsigned)o4.x);
        uint4 r1 = *reinterpret_cast<const uint4*>(tbs + (unsigned)o4.y);
        uint4 r2 = *reinterpret_cast<const uint4*>(tbs + (unsigned)o4.z);
        uint4 r3 = *reinterpret_cast<const uint4*>(tbs + (unsigned)o4.w);
        acc8(A, r0); acc8(B, r1); acc8(A, r2); acc8(B, r3);
    }
    for (; e < e1; ++e) {                       // tail <= 3 edges
        unsigned o = (unsigned)srcsB[e];
        uint4 r = *reinterpret_cast<const uint4*>(tbs + o);
        acc8(A, r);
    }
}

// Shared prologue + merged two-half gather. Self term is added in the half
// containing d (keeps every table access inside the currently-hot half).
#define GATHER_BOTH(tin)                                                       \
    int wv = (blockIdx.x * blockDim.x + threadIdx.x) >> 6;                     \
    int lane = threadIdx.x & 63;                                               \
    int g = lane / 5;                                                          \
    int sl = lane - g * 5;                                                     \
    if (g > 11) { g = 11; sl = 0; }                                            \
    int d = wv * 12 + g;                                                       \
    int act = (lane < 60) && (d < N);                                          \
    int dc = min(d, N - 1);                                                    \
    int e0 = starts[dc];                                                       \
    int m  = mid[dc];                                                          \
    int e1 = starts[dc + 1];                                                   \
    if (d >= N) { m = e0; e1 = e0; }                                           \
    int slo = sl << 4;                                                         \
    const char* tbs = (const char*)(tin) + slo;                                \
    F8 A = {0,0,0,0,0,0,0,0}, B = {0,0,0,0,0,0,0,0};                           \
    if (dc < HALF_SPLIT) {                      /* self in half0 phase */      \
        uint4 rs = *reinterpret_cast<const uint4*>(tbs + (size_t)dc * 80);     \
        acc8(A, rs);                                                           \
    }                                                                          \
    gather_range(tbs, srcsB, e0, m, A, B);      /* half0 edges */              \
    if (dc >= HALF_SPLIT) {                     /* self in half1 phase */      \
        uint4 rs = *reinterpret_cast<const uint4*>(tbs + (size_t)dc * 80);     \
        acc8(A, rs);                                                           \
    }                                                                          \
    gather_range(tbs, srcsB, m, e1, A, B);      /* half1 edges */              \
    A.v0 += B.v0; A.v1 += B.v1; A.v2 += B.v2; A.v3 += B.v3;                    \
    A.v4 += B.v4; A.v5 += B.v5; A.v6 += B.v6; A.v7 += B.v7;

// Middle hop (merged halves): tout[d] = f16( dd^2 * (t[d] + sum t[src]) ).
__global__ __launch_bounds__(256) void prop_hop(
    const unsigned short* __restrict__ tin, unsigned short* __restrict__ tout,
    const int* __restrict__ starts, const int* __restrict__ mid,
    const int* __restrict__ srcsB, const float* __restrict__ dis, int N)
{
    GATHER_BOTH(tin)
    if (act) {
        float dd = dis[dc];
        float sc = dd * dd;
        uint4 o;
        o.x = h2u(__floats2half2_rn(sc * A.v0, sc * A.v1));
        o.y = h2u(__floats2half2_rn(sc * A.v2, sc * A.v3));
        o.z = h2u(__floats2half2_rn(sc * A.v4, sc * A.v5));
        o.w = h2u(__floats2half2_rn(sc * A.v6, sc * A.v7));
        *reinterpret_cast<uint4*>((char*)tout + (size_t)d * 80 + slo) = o;
    }
}

// Final hop (merged halves) fused with bias + log_softmax. Softmax reduce =
// 4 rotate-shfls within the 5-lane group. Final stores NT (never re-read).
__global__ __launch_bounds__(256) void prop_fin(
    const unsigned short* __restrict__ tin, float* __restrict__ out,
    const int* __restrict__ starts, const int* __restrict__ mid,
    const int* __restrict__ srcsB, const float* __restrict__ dis,
    const float* __restrict__ bias, int N)
{
    GATHER_BOTH(tin)
    float dd = dis[dc];
    float4 blo = reinterpret_cast<const float4*>(bias)[sl * 2];       // sl<5
    float4 bhi = reinterpret_cast<const float4*>(bias)[sl * 2 + 1];
    float v0 = dd * A.v0 + blo.x, v1 = dd * A.v1 + blo.y;
    float v2 = dd * A.v2 + blo.z, v3 = dd * A.v3 + blo.w;
    float v4 = dd * A.v4 + bhi.x, v5 = dd * A.v5 + bhi.y;
    float v6 = dd * A.v6 + bhi.z, v7 = dd * A.v7 + bhi.w;
    float mx = fmaxf(fmaxf(fmaxf(v0, v1), fmaxf(v2, v3)),
                     fmaxf(fmaxf(v4, v5), fmaxf(v6, v7)));
    int rot = g * 5 + ((sl + 1 == 5) ? 0 : sl + 1);     // next lane in group
    float tmx = mx;
    #pragma unroll
    for (int k = 0; k < 4; ++k) { tmx = __shfl(tmx, rot); mx = fmaxf(mx, tmx); }
    float s = expf(v0 - mx) + expf(v1 - mx) + expf(v2 - mx) + expf(v3 - mx)
            + expf(v4 - mx) + expf(v5 - mx) + expf(v6 - mx) + expf(v7 - mx);
    float ts = s;
    #pragma unroll
    for (int k = 0; k < 4; ++k) { ts = __shfl(ts, rot); s += ts; }
    if (act) {
        float ls = mx + logf(s);
        float* ro = out + (size_t)d * N_CLASS + sl * 8;
        floatx4 lo = {v0 - ls, v1 - ls, v2 - ls, v3 - ls};
        floatx4 hi = {v4 - ls, v5 - ls, v6 - ls, v7 - ls};
        __builtin_nontemporal_store(lo, reinterpret_cast<floatx4*>(ro));
        __builtin_nontemporal_store(hi, reinterpret_cast<floatx4*>(ro) + 1);
    }
}

// ---------------------------------------------------------------------------
extern "C" void kernel_launch(void* const* d_in, const int* in_sizes, int n_in,
                              void* d_out, int out_size, void* d_ws, size_t ws_size,
                              hipStream_t stream) {
    const float* feature = (const float*)d_in[0];   // [N, 128]
    const float* weight  = (const float*)d_in[1];   // [40, 128]
    const float* bias    = (const float*)d_in[2];   // [40]
    const int*   ei      = (const int*)d_in[3];     // [2, E] (int32 or int64 words)
    const int N = N_NODES;
    const int E = in_sizes[3] / 2;

    size_t off = 0;
    auto take = [&](size_t bytes) { size_t o = off; off += (bytes + 255) & ~(size_t)255; return o; };
    char* ws = (char*)d_ws;
    int*   bCount    = (int*)  (ws + take((size_t)NBALLOC * 4));
    int*   starts    = (int*)  (ws + take((size_t)(N + 1) * 4));
    int*   mid       = (int*)  (ws + take((size_t)N * 4));
    float* dis       = (float*)(ws + take((size_t)N * 4));
    int*   srcsB     = (int*)  (ws + take((size_t)E * 4));
    // t0+t1 (16 MB contiguous) also host tmp (per-bucket record regions,
    // NBUSED*CAP*4 = 13.6 MB; tmp dead once p4 finishes, before transform)
    unsigned short* t0 = (unsigned short*)(ws + take((size_t)N * N_CLASS * 2));
    unsigned short* t1 = (unsigned short*)(ws + take((size_t)N * N_CLASS * 2));
    unsigned int* tmp = (unsigned int*)t0;

    // --- build CSR (single-level fine bucketed counting sort) ---
    hipMemsetAsync(bCount, 0, (size_t)NBALLOC * 4, stream);
    const int p3grid = (E + P3BLK - 1) / P3BLK;
    p3a_scatter<<<p3grid, P3THR, 0, stream>>>(ei, E, bCount, tmp);
    p4_sort<<<NBUSED, 256, 0, stream>>>(tmp, bCount, starts, mid, dis, srcsB, N, E);

    // --- transform (MFMA, pre-scaled f16 rows) then 2 merged-half hops ---
    const int ntile = (N + 15) / 16;
    const int tblocks = (ntile * 64 + 255) / 256;
    transform_mfma<<<tblocks, 256, 0, stream>>>(feature, weight, dis, t0, N);
    const int nwaves = (N + 11) / 12;                     // 12 nodes per wave
    const int nodeBlocks = (nwaves * 64 + 255) / 256;
    prop_hop<<<nodeBlocks, 256, 0, stream>>>(t0, t1, starts, mid, srcsB, dis, N);
    prop_fin<<<nodeBlocks, 256, 0, stream>>>(t1, (float*)d_out, starts, mid, srcsB,
                                             dis, bias, N);
}